// Round 18
// baseline (3921.019 us; speedup 1.0000x reference)
//
#include <hip/hip_runtime.h>

typedef unsigned short u16;
typedef __bf16 bf16_t;
typedef bf16_t bf16x8 __attribute__((ext_vector_type(8)));
typedef float f32x4 __attribute__((ext_vector_type(4)));
typedef unsigned int u32x4 __attribute__((ext_vector_type(4)));
typedef u16 u16x4 __attribute__((ext_vector_type(4)));

#define GL_LDS16(gp, lp)                                              \
  __builtin_amdgcn_global_load_lds(                                   \
      (const __attribute__((address_space(1))) void*)(gp),            \
      (__attribute__((address_space(3))) void*)(lp), 16, 0, 0)

__device__ __forceinline__ u16 f2bf(float f) {
  unsigned u = __builtin_bit_cast(unsigned, f);
  u += 0x7fff + ((u >> 16) & 1);   // RNE
  return (u16)(u >> 16);
}
__device__ __forceinline__ float bf2f(u16 h) {
  unsigned u = ((unsigned)h) << 16;
  return __builtin_bit_cast(float, u);
}
__device__ __forceinline__ float wredSum(float v) {
#pragma unroll
  for (int m = 32; m; m >>= 1) v += __shfl_xor(v, m);
  return v;
}
// tanh-form GELU via fast exp (~8 VALU ops). |err| <= ~1e-3.
__device__ __forceinline__ float gelu_fast(float v) {
  float t = 0.7978845608f * v * (1.f + 0.044715f * v * v);
  float e = __expf(2.f * t);
  float th = 1.f - 2.f / (e + 1.f);
  return 0.5f * v * (1.f + th);
}

// ==== persistent 128x128-tile bf16 NT GEMM, 2-buf / 5 blocks/CU (r18) ====
// C[M,N]=A[M,K]*B[N,K]^T. BK=32, 2 LDS buf x 16KB = 32KB -> 5 blocks/CU
// (160KB LDS), 20 waves/CU: max TLP for the latency-bound barrier chain
// (r17 counters: per-block K-tile ~3200cyc vs ~400cyc work; 3 barrier
// domains too few). Ledger (simplified): stage-1-ahead; iter s: vmcnt(0)
// [4 loads of tile s, issued 1 K-tile ago ~1000+cyc >> L2 latency] ->
// barrier -> stage(s+1) into buf (s+1)&1 [readers of that buf retired
// via lgkm before barrier(s)] -> ds_read buf s&1 -> MFMA. Tile boundary:
// epilogue stores + VM0 keeps ledger exact (stores count toward vmcnt).
// Supertile: XCD x owns mt-slab [x*G,(x+1)*G), G=gx/8.
__global__ __launch_bounds__(256, 5) void gemmq(
    const u16* __restrict__ A, const u16* __restrict__ B,
    const float* __restrict__ bias, u16* __restrict__ C,
    int K, int N, int gx, int gy, int act, int tstore) {
  __shared__ __align__(16) char sm[2 * 16384];  // 2 x (A 8KB | B 8KB)
  const int tid = threadIdx.x;
  const int l = tid & 63, w = tid >> 6, lg = l >> 4, li = l & 15;
  const int wr = w >> 1, wc = w & 1;
  const int TOT = gx * gy;
  int tix = blockIdx.x;
  if (tix >= TOT) return;
  const int G = gx >> 3;   // gx % 8 == 0

  const long rowK64 = (long)64 * K;
  const long saoff = (long)(tid >> 2) * K + (((tid & 3) ^ ((tid >> 3) & 3)) << 3);
  const int t16 = tid * 16;
  const int NPB = 1280;    // persistent stride (grid = 1280 blocks)

#define STAGE(bi_, Ap_, Bp_, kt_)                                      \
  do {                                                                 \
    char* lb_ = sm + (bi_) * 16384;                                    \
    const u16* ga_ = (Ap_) + saoff + ((long)(kt_) << 5);               \
    GL_LDS16(ga_, lb_ + t16);                                          \
    GL_LDS16(ga_ + rowK64, lb_ + 4096 + t16);                          \
    const u16* gb_ = (Bp_) + saoff + ((long)(kt_) << 5);               \
    GL_LDS16(gb_, lb_ + 8192 + t16);                                   \
    GL_LDS16(gb_ + rowK64, lb_ + 12288 + t16);                         \
  } while (0)

#define VM0 asm volatile("s_waitcnt vmcnt(0)" ::: "memory")

  // ds_read offsets (XOR swizzle slot' = lg ^ ((row>>1)&3); 0 conflicts)
  int aof[4], bof[4];
#pragma unroll
  for (int f = 0; f < 4; ++f) {
    int ra = wr * 64 + f * 16 + li;
    aof[f] = ra * 64 + ((lg ^ ((ra >> 1) & 3)) << 4);
    int rb = wc * 64 + f * 16 + li;
    bof[f] = 8192 + rb * 64 + ((lg ^ ((rb >> 1) & 3)) << 4);
  }

  int mt, nt;
  const u16 *cA, *cB;
  { int xc = tix & 7, lo = tix >> 3;
    mt = xc * G + lo % G; nt = lo / G;
    cA = A + (long)mt * 128 * K; cB = B + (long)nt * 128 * K; }
  int nxt = tix + NPB;
  int hasn = nxt < TOT;
  int nmt = 0, nnt = 0;
  const u16 *nA = cA, *nB = cB;
  if (hasn) { int xc = nxt & 7, lo = nxt >> 3;
    nmt = xc * G + lo % G; nnt = lo / G;
    nA = A + (long)nmt * 128 * K; nB = B + (long)nnt * 128 * K; }

  const int NT = K >> 5;  // K % 32 == 0, NT even
  f32x4 acc[4][4] = {};
  STAGE(0, cA, cB, 0);    // 4 loads in flight (tile unit 0)

  for (;;) {
    for (int s = 0; s < NT; ++s) {
      const char* ab = sm + (s & 1) * 16384;
      VM0;                                  // tile-s loads landed
      __builtin_amdgcn_s_barrier();
      asm volatile("" ::: "memory");        // no ds_read hoists above barrier
      int s1 = s + 1;
      if (s1 < NT) STAGE(s1 & 1, cA, cB, s1);
      else if (hasn) STAGE(0, nA, nB, 0);   // NT even -> next tile s=0 uses buf0
      bf16x8 af[4], bq[4];
#pragma unroll
      for (int f = 0; f < 4; ++f) {
        af[f] = __builtin_bit_cast(bf16x8, *(const u32x4*)(ab + aof[f]));
        bq[f] = __builtin_bit_cast(bf16x8, *(const u32x4*)(ab + bof[f]));
      }
      __builtin_amdgcn_s_setprio(1);
#pragma unroll
      for (int fi = 0; fi < 4; ++fi)
#pragma unroll
        for (int fj = 0; fj < 4; ++fj)
          acc[fi][fj] = __builtin_amdgcn_mfma_f32_16x16x32_bf16(af[fi], bq[fj], acc[fi][fj], 0, 0, 0);
      __builtin_amdgcn_s_setprio(0);
    }
    // ---- epilogue for current tile ----
    {
      long row0 = (long)mt * 128 + wr * 64;
      int col0 = nt * 128 + wc * 64;
#pragma unroll
      for (int fi = 0; fi < 4; ++fi) {
#pragma unroll
        for (int fj = 0; fj < 4; ++fj) {
          int c = col0 + fj * 16 + li;
          float bv = bias ? bias[c] : 0.f;
#pragma unroll
          for (int r = 0; r < 4; ++r) {
            float v = acc[fi][fj][r] + bv;
            if (act) v = gelu_fast(v);
            long row = row0 + fi * 16 + lg * 4 + r;
            long idx = tstore ? ((row >> 8) * 196608 + (long)c * 256 + (row & 255))
                              : (row * (long)N + c);
            C[idx] = f2bf(v);
          }
          acc[fi][fj] = (f32x4){0.f, 0.f, 0.f, 0.f};
        }
      }
    }
    if (!hasn) break;
    VM0;                    // drain epilogue stores: ledger stays exact
    mt = nmt; nt = nnt; cA = nA; cB = nB;
    tix = nxt; nxt += NPB; hasn = nxt < TOT;
    if (hasn) { int xc = nxt & 7, lo = nxt >> 3;
      nmt = xc * G + lo % G; nnt = lo / G;
      nA = A + (long)nmt * 128 * K; nB = B + (long)nnt * 128 * K; }
  }
#undef STAGE
#undef VM0
}

// ------- legacy 128x128 NT GEMM (semantic QK^T with +R epilogue, PV) -------
__global__ __launch_bounds__(256) void gemm_bt(
    const u16* __restrict__ A, const u16* __restrict__ B,
    const float* __restrict__ bias, const float* __restrict__ logdv,
    float* __restrict__ Cf, u16* __restrict__ Cb,
    int K, int ldc, long sA, long sB, long sC, float alpha, int act, int tstore) {
  __shared__ __align__(16) u16 As[2][128 * 32];
  __shared__ __align__(16) u16 Bs[2][128 * 32];
  int tid = threadIdx.x, w = tid >> 6, l = tid & 63, lg = l >> 4, li = l & 15;
  int wr = w >> 1, wc = w & 1;
  long bz = blockIdx.z;
  const u16* Ab = A + bz * sA + (long)blockIdx.x * 128 * K;
  const u16* Bb = B + bz * sB + (long)blockIdx.y * 128 * K;

  int sr = tid >> 2, ss = tid & 3;
  long ga0 = (long)sr * K + ((ss ^ ((sr >> 1) & 3)) << 3);
  long gstep = (long)K << 6;

  int aoff[4], boff[4];
#pragma unroll
  for (int i = 0; i < 4; ++i) {
    int ra = wr * 64 + i * 16 + li;
    aoff[i] = ra * 64 + ((lg ^ ((ra >> 1) & 3)) << 4);
    int rb = wc * 64 + i * 16 + li;
    boff[i] = rb * 64 + ((lg ^ ((rb >> 1) & 3)) << 4);
  }

  f32x4 acc[4][4] = {};
  int wb = w * 1024;

  GL_LDS16(Ab + ga0, (char*)As + wb);
  GL_LDS16(Ab + ga0 + gstep, (char*)As + 4096 + wb);
  GL_LDS16(Bb + ga0, (char*)Bs + wb);
  GL_LDS16(Bb + ga0 + gstep, (char*)Bs + 4096 + wb);
  __syncthreads();

  int T = K >> 5;
  int bsel = 0;
  for (int kt = 0; kt < T; ++kt) {
    if (kt + 1 < T) {
      long ko = (long)(kt + 1) << 5;
      char* an = (char*)As + (bsel ^ 1) * 8192;
      char* bn = (char*)Bs + (bsel ^ 1) * 8192;
      GL_LDS16(Ab + ga0 + ko, an + wb);
      GL_LDS16(Ab + ga0 + gstep + ko, an + 4096 + wb);
      GL_LDS16(Bb + ga0 + ko, bn + wb);
      GL_LDS16(Bb + ga0 + gstep + ko, bn + 4096 + wb);
    }
    char* ac = (char*)As + bsel * 8192;
    char* bc = (char*)Bs + bsel * 8192;
    bf16x8 af[4], bq[4];
#pragma unroll
    for (int i = 0; i < 4; ++i) {
      af[i] = __builtin_bit_cast(bf16x8, *(const u32x4*)(ac + aoff[i]));
      bq[i] = __builtin_bit_cast(bf16x8, *(const u32x4*)(bc + boff[i]));
    }
#pragma unroll
    for (int i = 0; i < 4; ++i)
#pragma unroll
      for (int j = 0; j < 4; ++j)
        acc[i][j] = __builtin_amdgcn_mfma_f32_16x16x32_bf16(af[i], bq[j], acc[i][j], 0, 0, 0);
    __syncthreads();
    bsel ^= 1;
  }

  long row0 = (long)blockIdx.x * 128 + wr * 64;
  int col0 = blockIdx.y * 128 + wc * 64;
  float* cf = Cf ? Cf + bz * sC : (float*)0;
  u16* cb = Cb ? Cb + bz * sC : (u16*)0;
  const float* ldv = logdv ? logdv + bz * 256 : (const float*)0;
#pragma unroll
  for (int i = 0; i < 4; ++i) {
    long rb0 = row0 + i * 16 + lg * 4;
#pragma unroll
    for (int j = 0; j < 4; ++j) {
      int c = col0 + j * 16 + li;
      float bv = bias ? bias[c] : 0.f;
      float lj = ldv ? ldv[c] : 0.f;
#pragma unroll
      for (int r = 0; r < 4; ++r) {
        float v = acc[i][j][r] * alpha + bv;
        if (ldv) v += fabsf(ldv[rb0 + r] - lj);
        if (act) v = 0.5f * v * (1.f + erff(v * 0.70710678118f));
        long row = rb0 + r;
        long idx = tstore ? ((row >> 8) * 196608 + (long)c * 256 + (row & 255))
                          : (row * ldc + c);
        if (cf) cf[idx] = v;
        if (cb) cb[idx] = f2bf(v);
      }
    }
  }
}

// ------- fused MHA: one block per (b, h); 8 waves; K/V staged ONCE -------
// 512 threads. LDS (dynamic 128KB): Ks 32KB | Vt 32KB | Ps 64KB (8KB/wave).
__global__ __launch_bounds__(512) void mha_k(const u16* __restrict__ qkv, u16* __restrict__ obf) {
  extern __shared__ __align__(16) char smh[];
  u16* Ks = (u16*)smh;                  // [256][64] swizzled
  u16* Vt = (u16*)(smh + 32768);        // [64][256] swizzled
  char* Pw0 = smh + 65536;              // per-wave [16][256] swizzled
  int b = blockIdx.y;
  int h = blockIdx.x;
  int tid = threadIdx.x, w = tid >> 6, l = tid & 63, lg = l >> 4, li = l & 15;
  const u16* kb_ = qkv + (long)b * 256 * 2304 + 768 + h * 64;
  const u16* vb_ = qkv + (long)b * 256 * 2304 + 1536 + h * 64;
#pragma unroll
  for (int it = 0; it < 4; ++it) {
    int c = it * 512 + tid; int n = c >> 3, sl = c & 7;
    u32x4 d = *(const u32x4*)(kb_ + (long)n * 2304 + sl * 8);
    *(u32x4*)((char*)Ks + n * 128 + ((sl ^ (n & 7)) << 4)) = d;
  }
#pragma unroll
  for (int it = 0; it < 4; ++it) {
    int c = it * 512 + tid; int n = c >> 3, sl = c & 7;
    u32x4 dv = *(const u32x4*)(vb_ + (long)n * 2304 + sl * 8);
    const u16* pe = (const u16*)&dv;
#pragma unroll
    for (int j = 0; j < 8; ++j) {
      int dd = sl * 8 + j;
      *(u16*)((char*)Vt + dd * 512 + (((n >> 3) ^ (dd & 7)) << 4) + (n & 7) * 2) = pe[j];
    }
  }
  __syncthreads();

  char* Ps = Pw0 + w * 8192;
  for (int half = 0; half < 2; ++half) {
    long qrow = (long)b * 256 + half * 128 + w * 16 + li;
    const u16* qp = qkv + qrow * 2304 + h * 64;
    bf16x8 qf0 = __builtin_bit_cast(bf16x8, *(const u32x4*)(qp + lg * 8));
    bf16x8 qf1 = __builtin_bit_cast(bf16x8, *(const u32x4*)(qp + 32 + lg * 8));

    f32x4 sacc[16] = {};
#pragma unroll
    for (int jt = 0; jt < 16; ++jt) {
      int j = jt * 16 + li;
      u32x4 k0 = *(const u32x4*)((char*)Ks + j * 128 + ((lg ^ (j & 7)) << 4));
      u32x4 k1 = *(const u32x4*)((char*)Ks + j * 128 + (((4 + lg) ^ (j & 7)) << 4));
      sacc[jt] = __builtin_amdgcn_mfma_f32_16x16x32_bf16(qf0, __builtin_bit_cast(bf16x8, k0), sacc[jt], 0, 0, 0);
      sacc[jt] = __builtin_amdgcn_mfma_f32_16x16x32_bf16(qf1, __builtin_bit_cast(bf16x8, k1), sacc[jt], 0, 0, 0);
    }
#pragma unroll
    for (int jt = 0; jt < 16; ++jt) sacc[jt] = sacc[jt] * 0.125f;

    float rinv[4];
#pragma unroll
    for (int r = 0; r < 4; ++r) {
      float m = -1e30f;
#pragma unroll
      for (int jt = 0; jt < 16; ++jt) m = fmaxf(m, sacc[jt][r]);
#pragma unroll
      for (int mk = 1; mk < 16; mk <<= 1) m = fmaxf(m, __shfl_xor(m, mk));
      float s = 0.f;
#pragma unroll
      for (int jt = 0; jt < 16; ++jt) { float e = __expf(sacc[jt][r] - m); sacc[jt][r] = e; s += e; }
#pragma unroll
      for (int mk = 1; mk < 16; mk <<= 1) s += __shfl_xor(s, mk);
      rinv[r] = 1.f / s;
    }
#pragma unroll
    for (int jt = 0; jt < 16; ++jt) {
      int j = jt * 16 + li;
#pragma unroll
      for (int r = 0; r < 4; ++r) {
        int i = lg * 4 + r;
        *(u16*)(Ps + i * 512 + (((j >> 3) ^ (i & 7)) << 4) + (j & 7) * 2) = f2bf(sacc[jt][r]);
      }
    }
    __syncthreads();
    f32x4 oacc[4] = {};
#pragma unroll
    for (int kb2 = 0; kb2 < 8; ++kb2) {
      int sl = kb2 * 4 + lg;
      u32x4 pa = *(const u32x4*)(Ps + li * 512 + ((sl ^ (li & 7)) << 4));
#pragma unroll
      for (int dt = 0; dt < 4; ++dt) {
        int dd = dt * 16 + li;
        u32x4 vv = *(const u32x4*)((char*)Vt + dd * 512 + ((sl ^ (dd & 7)) << 4));
        oacc[dt] = __builtin_amdgcn_mfma_f32_16x16x32_bf16(__builtin_bit_cast(bf16x8, pa),
                                                           __builtin_bit_cast(bf16x8, vv), oacc[dt], 0, 0, 0);
      }
    }
    long orow = (long)b * 256 + half * 128 + w * 16;
#pragma unroll
    for (int dt = 0; dt < 4; ++dt)
#pragma unroll
      for (int r = 0; r < 4; ++r) {
        float vvv = oacc[dt][r] * rinv[r];
        obf[(orow + lg * 4 + r) * 768 + h * 64 + dt * 16 + li] = f2bf(vvv);
      }
  }
}

// -------- LayerNorm(x + res), all bf16 in / bf16 out (wave per row) --------
__global__ __launch_bounds__(256) void ln_k(const u16* __restrict__ X, const u16* __restrict__ Rr,
                                            const float* __restrict__ g, const float* __restrict__ bb,
                                            u16* __restrict__ O) {
  long row = (long)blockIdx.x * 4 + (threadIdx.x >> 6);
  int l = threadIdx.x & 63;
  const u16* x = X + row * 768;
  const u16* rr = Rr + row * 768;
  f32x4 v[3];
  float s = 0.f;
#pragma unroll
  for (int i = 0; i < 3; ++i) {
    u16x4 xv = *(const u16x4*)(x + i * 256 + l * 4);
    u16x4 rv = *(const u16x4*)(rr + i * 256 + l * 4);
    f32x4 t;
#pragma unroll
    for (int j = 0; j < 4; ++j) t[j] = bf2f(xv[j]) + bf2f(rv[j]);
    v[i] = t;
    s += t[0] + t[1] + t[2] + t[3];
  }
  float mean = wredSum(s) * (1.f / 768.f);
  float q = 0.f;
#pragma unroll
  for (int i = 0; i < 3; ++i) {
#pragma unroll
    for (int j = 0; j < 4; ++j) { v[i][j] -= mean; q += v[i][j] * v[i][j]; }
  }
  float inv = rsqrtf(wredSum(q) * (1.f / 768.f) + 1e-5f);
#pragma unroll
  for (int i = 0; i < 3; ++i) {
    f32x4 gv = *(const f32x4*)(g + i * 256 + l * 4);
    f32x4 bv = *(const f32x4*)(bb + i * 256 + l * 4);
    u16x4 ob;
#pragma unroll
    for (int j = 0; j < 4; ++j) ob[j] = f2bf(v[i][j] * inv * gv[j] + bv[j]);
    *(u16x4*)(O + row * 768 + i * 256 + l * 4) = ob;
  }
}

// ---------------- semantic softmax ----------------
__global__ __launch_bounds__(256) void smax_k(const float* __restrict__ S, u16* __restrict__ P) {
  long row = (long)blockIdx.x * 4 + (threadIdx.x >> 6);
  int l = threadIdx.x & 63;
  f32x4 v = *(const f32x4*)(S + row * 256 + l * 4);
  float m = fmaxf(fmaxf(v[0], v[1]), fmaxf(v[2], v[3]));
#pragma unroll
  for (int mk = 1; mk < 64; mk <<= 1) m = fmaxf(m, __shfl_xor(m, mk));
  float e0 = __expf(v[0] - m), e1 = __expf(v[1] - m), e2 = __expf(v[2] - m), e3 = __expf(v[3] - m);
  float s = wredSum(e0 + e1 + e2 + e3);
  float rn = 1.f / s;
  u16x4 o; o[0] = f2bf(e0 * rn); o[1] = f2bf(e1 * rn); o[2] = f2bf(e2 * rn); o[3] = f2bf(e3 * rn);
  *(u16x4*)(P + row * 256 + l * 4) = o;
}

__global__ __launch_bounds__(256) void conv_k(const float* __restrict__ in, u16* __restrict__ out, long n4) {
  long i = (long)blockIdx.x * 256 + threadIdx.x;
  if (i >= n4) return;
  f32x4 v = *(const f32x4*)(in + i * 4);
  u16x4 o; o[0] = f2bf(v[0]); o[1] = f2bf(v[1]); o[2] = f2bf(v[2]); o[3] = f2bf(v[3]);
  *(u16x4*)(out + i * 4) = o;
}

// ---------------- concat ocr/obj -> x bf16 ----------------
__global__ __launch_bounds__(256) void concat_k(const float* __restrict__ ocr, const float* __restrict__ obj,
                                                u16* __restrict__ xb) {
  long i = (long)blockIdx.x * 256 + threadIdx.x;
  if (i >= 16384L * 192) return;
  long row = i / 192; int c4 = (int)(i % 192);
  int b = (int)(row >> 8), n = (int)(row & 255);
  const float* src = (n < 64) ? (ocr + ((long)(b * 64 + n)) * 768) : (obj + ((long)(b * 192 + n - 64)) * 768);
  f32x4 v = *(const f32x4*)(src + c4 * 4);
  u16x4 o; o[0] = f2bf(v[0]); o[1] = f2bf(v[1]); o[2] = f2bf(v[2]); o[3] = f2bf(v[3]);
  *(u16x4*)(xb + row * 768 + c4 * 4) = o;
}

__global__ __launch_bounds__(256) void logdv_k(const float* __restrict__ ocr_dv, const float* __restrict__ obj_dv,
                                               float* __restrict__ out) {
  int i = blockIdx.x * 256 + threadIdx.x;
  if (i >= 16384) return;
  int b = i >> 8, n = i & 255;
  float dv = (n < 64) ? ocr_dv[b * 64 + n] : obj_dv[b * 192 + n - 64];
  out[i] = logf(dv);
}

// ---------------- output slice h[:, :64, :] bf16 -> f32 ----------------
__global__ __launch_bounds__(256) void slice_k(const u16* __restrict__ H, float* __restrict__ O) {
  long i = (long)blockIdx.x * 256 + threadIdx.x;
  if (i >= 786432) return;
  long idx = i * 4;
  long row = idx / 768; int c = (int)(idx % 768);
  long b = row >> 6, n = row & 63;
  u16x4 v = *(const u16x4*)(H + ((b * 256 + n) * 768 + c));
  f32x4 o; o[0] = bf2f(v[0]); o[1] = bf2f(v[1]); o[2] = bf2f(v[2]); o[3] = bf2f(v[3]);
  *(f32x4*)(O + idx) = o;
}

extern "C" void kernel_launch(void* const* d_in, const int* in_sizes, int n_in,
                              void* d_out, int out_size, void* d_ws, size_t ws_size,
                              hipStream_t stream) {
  const float* ocr = (const float*)d_in[0];
  const float* obj = (const float*)d_in[1];
  const float* ocr_dv = (const float*)d_in[2];
  const float* obj_dv = (const float*)d_in[3];
  const float* sa_wq = (const float*)d_in[4];
  const float* sa_bq = (const float*)d_in[5];
  const float* sa_wk = (const float*)d_in[6];
  const float* sa_bk = (const float*)d_in[7];
  const float* sa_wv = (const float*)d_in[8];
  const float* sa_bv = (const float*)d_in[9];
  const float* ln0_g = (const float*)d_in[10];
  const float* ln0_b = (const float*)d_in[11];
  const float* qkv_w = (const float*)d_in[12];
  const float* qkv_b = (const float*)d_in[13];
  const float* out_w = (const float*)d_in[14];
  const float* out_b = (const float*)d_in[15];
  const float* ln1_g = (const float*)d_in[16];
  const float* ln1_b = (const float*)d_in[17];
  const float* ff1_w = (const float*)d_in[18];
  const float* ff1_b = (const float*)d_in[19];
  const float* ff2_w = (const float*)d_in[20];
  const float* ff2_b = (const float*)d_in[21];
  const float* ln2_g = (const float*)d_in[22];
  const float* ln2_b = (const float*)d_in[23];

  (void)hipFuncSetAttribute((const void*)mha_k,
                            hipFuncAttributeMaxDynamicSharedMemorySize, 131072);
  const unsigned DSMHA = 131072;

  char* ws = (char*)d_ws;
  u16* HB = (u16*)ws;                            // h bf16 [16384][768] 25.2MB
  float* LDV = (float*)(ws + 25165824);          // log(dv)             64KB

  const int bigws = ws_size >= (size_t)187236352;

  auto cv = [&](const float* src, long elems, u16* dst) {
    long n4 = elems >> 2;
    conv_k<<<dim3((unsigned)((n4 + 255) / 256)), dim3(256), 0, stream>>>(src, dst, n4);
  };

  concat_k<<<12288, 256, 0, stream>>>(ocr, obj, HB);
  logdv_k<<<64, 256, 0, stream>>>(ocr_dv, obj_dv, LDV);

  const float SSC = 0.03608439182435161f;  // 1/sqrt(768)

  if (bigws) {
    // layout: HB 25.2MB | LDV 64KB | WALL 47.6MB (all weights bf16) | SCR 101.7MB
    u16* WALL = (u16*)(ws + 25231360);
    u16* WSA = WALL;                                // 3 x 589824 semantic
    cv(sa_wq, 589824, WSA);
    cv(sa_wk, 589824, WSA + 589824);
    cv(sa_wv, 589824, WSA + 1179648);
    for (int l = 0; l < 4; ++l) {
      u16* WL = WALL + 1769472 + (long)l * 5505024;
      cv(qkv_w + (long)l * 1769472, 1769472, WL);
      cv(out_w + (long)l * 589824, 589824, WL + 1769472);
      cv(ff1_w + (long)l * 1572864, 1572864, WL + 2359296);
      cv(ff2_w + (long)l * 1572864, 1572864, WL + 3932160);
    }
    char* SCR = ws + 25231360 + 47579136;           // total 174.5MB
    // ---------- semantic attention, full-M single pass ----------
    u16* Qf = (u16*)SCR;                         // [16384][768]  25.2MB
    u16* Kf = (u16*)(SCR + 25165824);            // [16384][768]  25.2MB
    u16* VTf = (u16*)(SCR + 50331648);           // [64][768][256] 25.2MB
    float* Sff = (float*)(SCR + 75497472);       // [64][256][256] f32 16.8MB
    u16* Pf = (u16*)SCR;                         // (Q dead)
    u16* ATTf = (u16*)(SCR + 25165824);          // (K dead)
    gemmq<<<1280, 256, 0, stream>>>(HB, WSA, sa_bq, Qf, 768, 768, 128, 6, 0, 0);
    gemmq<<<1280, 256, 0, stream>>>(HB, WSA + 589824, sa_bk, Kf, 768, 768, 128, 6, 0, 0);
    gemmq<<<1280, 256, 0, stream>>>(HB, WSA + 1179648, sa_bv, VTf, 768, 768, 128, 6, 0, 1);
    gemm_bt<<<dim3(2, 2, 64), 256, 0, stream>>>(Qf, Kf, nullptr, LDV, Sff, nullptr, 768, 256,
                                                196608, 196608, 65536, SSC, 0, 0);
    smax_k<<<4096, 256, 0, stream>>>(Sff, Pf);
    gemm_bt<<<dim3(2, 6, 64), 256, 0, stream>>>(Pf, VTf, nullptr, nullptr,
                                                nullptr, ATTf, 256, 768, 65536, 196608, 196608, 1.f, 0, 0);
    ln_k<<<4096, 256, 0, stream>>>(HB, ATTf, ln0_g, ln0_b, HB);
    // ---------- 4 encoder layers, full-M ----------
    u16* QKVf = (u16*)SCR;                       // [16384][2304] 75.5MB
    u16* Of = (u16*)(SCR + 75497472);            // [16384][768]  25.2MB
    u16* PRf = (u16*)SCR;                        // (QKV dead)
    u16* FFf = (u16*)(SCR + 25165824);           // (O dead)
    for (int l = 0; l < 4; ++l) {
      u16* WL = WALL + 1769472 + (long)l * 5505024;
      gemmq<<<1280, 256, 0, stream>>>(HB, WL, qkv_b + l * 2304, QKVf, 768, 2304, 128, 18, 0, 0);
      mha_k<<<dim3(12, 64), 512, DSMHA, stream>>>(QKVf, Of);
      gemmq<<<1280, 256, 0, stream>>>(Of, WL + 1769472, out_b + l * 768, PRf, 768, 768, 128, 6, 0, 0);
      ln_k<<<4096, 256, 0, stream>>>(HB, PRf, ln1_g + l * 768, ln1_b + l * 768, HB);
      gemmq<<<1280, 256, 0, stream>>>(HB, WL + 2359296, ff1_b + l * 2048, FFf, 768, 2048, 128, 16, 1, 0);
      gemmq<<<1280, 256, 0, stream>>>(FFf, WL + 3932160, ff2_b + l * 768, PRf, 2048, 768, 128, 6, 0, 0);
      ln_k<<<4096, 256, 0, stream>>>(HB, PRf, ln2_g + l * 768, ln2_b + l * 768, HB);
    }
  } else {
    // ---------- fallback: rotating 11MB weight buf + chunked (proven) ----------
    u16* WCV = (u16*)(ws + 25231360);
    char* SCR = ws + 36241408;
    cv(sa_wq, 589824, WCV);
    cv(sa_wk, 589824, WCV + 589824);
    cv(sa_wv, 589824, WCV + 1179648);
    for (int c = 0; c < 2; ++c) {
      long base = (long)c * 8192;
      u16* Qc = (u16*)SCR;
      u16* Kc = (u16*)(SCR + 12582912);
      u16* VTc = (u16*)(SCR + 25165824);
      float* Sfc = (float*)(SCR + 37748736);
      u16* Pc = (u16*)(SCR + 46137344);
      u16* ATTc = (u16*)(SCR + 50331648);
      gemmq<<<1280, 256, 0, stream>>>(HB + base * 768, WCV, sa_bq, Qc, 768, 768, 64, 6, 0, 0);
      gemmq<<<1280, 256, 0, stream>>>(HB + base * 768, WCV + 589824, sa_bk, Kc, 768, 768, 64, 6, 0, 0);
      gemmq<<<1280, 256, 0, stream>>>(HB + base * 768, WCV + 1179648, sa_bv, VTc, 768, 768, 64, 6, 0, 1);
      gemm_bt<<<dim3(2, 2, 32), 256, 0, stream>>>(Qc, Kc, nullptr, LDV + c * 8192,
                                                  Sfc, nullptr, 768, 256, 196608, 196608, 65536, SSC, 0, 0);
      smax_k<<<2048, 256, 0, stream>>>(Sfc, Pc);
      gemm_bt<<<dim3(2, 6, 32), 256, 0, stream>>>(Pc, VTc, nullptr, nullptr,
                                                  nullptr, ATTc, 256, 768, 65536, 196608, 196608, 1.f, 0, 0);
      ln_k<<<2048, 256, 0, stream>>>(HB + base * 768, ATTc, ln0_g, ln0_b, HB + base * 768);
    }
    for (int l = 0; l < 4; ++l) {
      cv(qkv_w + (long)l * 1769472, 1769472, WCV);
      cv(out_w + (long)l * 589824, 589824, WCV + 1769472);
      cv(ff1_w + (long)l * 1572864, 1572864, WCV + 2359296);
      cv(ff2_w + (long)l * 1572864, 1572864, WCV + 3932160);
      for (int c = 0; c < 2; ++c) {
        long base = (long)c * 8192;
        u16* QKVc = (u16*)SCR;
        u16* Oc = (u16*)(SCR + 37748736);
        u16* PRc = (u16*)(SCR + 50331648);
        u16* FFc = (u16*)SCR;
        gemmq<<<1280, 256, 0, stream>>>(HB + base * 768, WCV, qkv_b + l * 2304, QKVc, 768, 2304, 64, 18, 0, 0);
        mha_k<<<dim3(12, 32), 512, DSMHA, stream>>>(QKVc, Oc);
        gemmq<<<1280, 256, 0, stream>>>(Oc, WCV + 1769472, out_b + l * 768, PRc, 768, 768, 64, 6, 0, 0);
        ln_k<<<2048, 256, 0, stream>>>(HB + base * 768, PRc, ln1_g + l * 768, ln1_b + l * 768, HB + base * 768);
        gemmq<<<1280, 256, 0, stream>>>(HB + base * 768, WCV + 2359296, ff1_b + l * 2048, FFc, 768, 2048, 64, 16, 1, 0);
        gemmq<<<1280, 256, 0, stream>>>(FFc, WCV + 3932160, ff2_b + l * 768, PRc, 2048, 768, 64, 6, 0, 0);
        ln_k<<<2048, 256, 0, stream>>>(HB + base * 768, PRc, ln2_g + l * 768, ln2_b + l * 768, HB + base * 768);
      }
    }
  }
  slice_k<<<3072, 256, 0, stream>>>(HB, (float*)d_out);
}

// Round 19
// 1626.080 us; speedup vs baseline: 2.4113x; 2.4113x over previous
//
#include <hip/hip_runtime.h>

typedef unsigned short u16;
typedef __bf16 bf16_t;
typedef bf16_t bf16x8 __attribute__((ext_vector_type(8)));
typedef float f32x4 __attribute__((ext_vector_type(4)));
typedef unsigned int u32x4 __attribute__((ext_vector_type(4)));
typedef u16 u16x4 __attribute__((ext_vector_type(4)));

#define GL_LDS16(gp, lp)                                              \
  __builtin_amdgcn_global_load_lds(                                   \
      (const __attribute__((address_space(1))) void*)(gp),            \
      (__attribute__((address_space(3))) void*)(lp), 16, 0, 0)

__device__ __forceinline__ u16 f2bf(float f) {
  unsigned u = __builtin_bit_cast(unsigned, f);
  u += 0x7fff + ((u >> 16) & 1);   // RNE
  return (u16)(u >> 16);
}
__device__ __forceinline__ float bf2f(u16 h) {
  unsigned u = ((unsigned)h) << 16;
  return __builtin_bit_cast(float, u);
}
__device__ __forceinline__ float wredSum(float v) {
#pragma unroll
  for (int m = 32; m; m >>= 1) v += __shfl_xor(v, m);
  return v;
}
// tanh-form GELU via fast exp (~8 VALU ops). |err| <= ~1e-3.
__device__ __forceinline__ float gelu_fast(float v) {
  float t = 0.7978845608f * v * (1.f + 0.044715f * v * v);
  float e = __expf(2.f * t);
  float th = 1.f - 2.f / (e + 1.f);
  return 0.5f * v * (1.f + th);
}

// ===== persistent 128x128-tile rolling bf16 NT GEMM, 3 blocks/CU (r17) =====
// C[M,N]=A[M,K]*B[N,K]^T. BK=32, 3 LDS buf x 16KB = 48KB static
// -> 3 blocks/CU (144KB), 12 waves/CU, 68 VGPR (no spill; r18's 5 blocks/CU
// capped VGPR at ~96 -> acc spilled to scratch, WRITE 80->718MB, 2.4x slower).
// Ledger: prologue u0,u1 (8 in flight); iter s: vmcnt(4) [retire u_s]
// -> barrier -> stage u_{s+2} -> ds_read -> MFMA. Epilogue ends with VM0
// (stores count toward vmcnt; ledger stays exact across tiles).
// Supertile: XCD x owns mt-slab [x*G,(x+1)*G), G=gx/8.
__global__ __launch_bounds__(256, 3) void gemmq(
    const u16* __restrict__ A, const u16* __restrict__ B,
    const float* __restrict__ bias, u16* __restrict__ C,
    int K, int N, int gx, int gy, int act, int tstore) {
  __shared__ __align__(16) char sm[3 * 16384];  // 3 x (A 8KB | B 8KB)
  const int tid = threadIdx.x;
  const int l = tid & 63, w = tid >> 6, lg = l >> 4, li = l & 15;
  const int wr = w >> 1, wc = w & 1;
  const int TOT = gx * gy;
  int tix = blockIdx.x;
  if (tix >= TOT) return;
  const int G = gx >> 3;   // gx % 8 == 0

  const long rowK64 = (long)64 * K;
  const long saoff = (long)(tid >> 2) * K + (((tid & 3) ^ ((tid >> 3) & 3)) << 3);
  const int t16 = tid * 16;

#define STAGE(bi_, Ap_, Bp_, kt_)                                      \
  do {                                                                 \
    char* lb_ = sm + (bi_) * 16384;                                    \
    const u16* ga_ = (Ap_) + saoff + ((long)(kt_) << 5);               \
    GL_LDS16(ga_, lb_ + t16);                                          \
    GL_LDS16(ga_ + rowK64, lb_ + 4096 + t16);                          \
    const u16* gb_ = (Bp_) + saoff + ((long)(kt_) << 5);               \
    GL_LDS16(gb_, lb_ + 8192 + t16);                                   \
    GL_LDS16(gb_ + rowK64, lb_ + 12288 + t16);                         \
  } while (0)

#define VM4 asm volatile("s_waitcnt vmcnt(4)" ::: "memory")
#define VM0 asm volatile("s_waitcnt vmcnt(0)" ::: "memory")

  // ds_read offsets (XOR swizzle slot' = lg ^ ((row>>1)&3); 0 conflicts)
  int aof[4], bof[4];
#pragma unroll
  for (int f = 0; f < 4; ++f) {
    int ra = wr * 64 + f * 16 + li;
    aof[f] = ra * 64 + ((lg ^ ((ra >> 1) & 3)) << 4);
    int rb = wc * 64 + f * 16 + li;
    bof[f] = 8192 + rb * 64 + ((lg ^ ((rb >> 1) & 3)) << 4);
  }

  int mt, nt;
  const u16 *cA, *cB;
  { int xc = tix & 7, lo = tix >> 3;
    mt = xc * G + lo % G; nt = lo / G;
    cA = A + (long)mt * 128 * K; cB = B + (long)nt * 128 * K; }
  int nxt = tix + 768;
  int hasn = nxt < TOT;
  int nmt = 0, nnt = 0;
  const u16 *nA = cA, *nB = cB;
  if (hasn) { int xc = nxt & 7, lo = nxt >> 3;
    nmt = xc * G + lo % G; nnt = lo / G;
    nA = A + (long)nmt * 128 * K; nB = B + (long)nnt * 128 * K; }

  const int NT = K >> 5;  // K % 32 == 0, NT >= 3
  f32x4 acc[4][4] = {};
  STAGE(0, cA, cB, 0); STAGE(1, cA, cB, 1);  // 8 loads in flight
  int bi = 0;

  for (;;) {
    for (int s = 0; s < NT; ++s) {
      int bi2 = bi + 2; if (bi2 >= 3) bi2 -= 3;
      const char* ab = sm + bi * 16384;
      if (s == NT - 1 && !hasn) VM0; else VM4;
      __builtin_amdgcn_s_barrier();
      asm volatile("" ::: "memory");        // no ds_read hoists above barrier
      int s2 = s + 2;
      if (s2 < NT) STAGE(bi2, cA, cB, s2);
      else if (hasn) STAGE(bi2, nA, nB, s2 - NT);
      bf16x8 af[4], bq[4];
#pragma unroll
      for (int f = 0; f < 4; ++f) {
        af[f] = __builtin_bit_cast(bf16x8, *(const u32x4*)(ab + aof[f]));
        bq[f] = __builtin_bit_cast(bf16x8, *(const u32x4*)(ab + bof[f]));
      }
      __builtin_amdgcn_s_setprio(1);
#pragma unroll
      for (int fi = 0; fi < 4; ++fi)
#pragma unroll
        for (int fj = 0; fj < 4; ++fj)
          acc[fi][fj] = __builtin_amdgcn_mfma_f32_16x16x32_bf16(af[fi], bq[fj], acc[fi][fj], 0, 0, 0);
      __builtin_amdgcn_s_setprio(0);
      bi = bi + 1; if (bi == 3) bi = 0;
    }
    // ---- epilogue for current tile ----
    {
      long row0 = (long)mt * 128 + wr * 64;
      int col0 = nt * 128 + wc * 64;
#pragma unroll
      for (int fi = 0; fi < 4; ++fi) {
#pragma unroll
        for (int fj = 0; fj < 4; ++fj) {
          int c = col0 + fj * 16 + li;
          float bv = bias ? bias[c] : 0.f;
#pragma unroll
          for (int r = 0; r < 4; ++r) {
            float v = acc[fi][fj][r] + bv;
            if (act) v = gelu_fast(v);
            long row = row0 + fi * 16 + lg * 4 + r;
            long idx = tstore ? ((row >> 8) * 196608 + (long)c * 256 + (row & 255))
                              : (row * (long)N + c);
            C[idx] = f2bf(v);
          }
          acc[fi][fj] = (f32x4){0.f, 0.f, 0.f, 0.f};
        }
      }
    }
    if (!hasn) break;
    VM0;                    // drain epilogue stores: ledger stays exact
    mt = nmt; nt = nnt; cA = nA; cB = nB;
    tix = nxt; nxt += 768; hasn = nxt < TOT;
    if (hasn) { int xc = nxt & 7, lo = nxt >> 3;
      nmt = xc * G + lo % G; nnt = lo / G;
      nA = A + (long)nmt * 128 * K; nB = B + (long)nnt * 128 * K; }
  }
#undef STAGE
#undef VM4
#undef VM0
}

// ------- legacy 128x128 NT GEMM (semantic QK^T with +R epilogue, PV) -------
__global__ __launch_bounds__(256) void gemm_bt(
    const u16* __restrict__ A, const u16* __restrict__ B,
    const float* __restrict__ bias, const float* __restrict__ logdv,
    float* __restrict__ Cf, u16* __restrict__ Cb,
    int K, int ldc, long sA, long sB, long sC, float alpha, int act, int tstore) {
  __shared__ __align__(16) u16 As[2][128 * 32];
  __shared__ __align__(16) u16 Bs[2][128 * 32];
  int tid = threadIdx.x, w = tid >> 6, l = tid & 63, lg = l >> 4, li = l & 15;
  int wr = w >> 1, wc = w & 1;
  long bz = blockIdx.z;
  const u16* Ab = A + bz * sA + (long)blockIdx.x * 128 * K;
  const u16* Bb = B + bz * sB + (long)blockIdx.y * 128 * K;

  int sr = tid >> 2, ss = tid & 3;
  long ga0 = (long)sr * K + ((ss ^ ((sr >> 1) & 3)) << 3);
  long gstep = (long)K << 6;

  int aoff[4], boff[4];
#pragma unroll
  for (int i = 0; i < 4; ++i) {
    int ra = wr * 64 + i * 16 + li;
    aoff[i] = ra * 64 + ((lg ^ ((ra >> 1) & 3)) << 4);
    int rb = wc * 64 + i * 16 + li;
    boff[i] = rb * 64 + ((lg ^ ((rb >> 1) & 3)) << 4);
  }

  f32x4 acc[4][4] = {};
  int wb = w * 1024;

  GL_LDS16(Ab + ga0, (char*)As + wb);
  GL_LDS16(Ab + ga0 + gstep, (char*)As + 4096 + wb);
  GL_LDS16(Bb + ga0, (char*)Bs + wb);
  GL_LDS16(Bb + ga0 + gstep, (char*)Bs + 4096 + wb);
  __syncthreads();

  int T = K >> 5;
  int bsel = 0;
  for (int kt = 0; kt < T; ++kt) {
    if (kt + 1 < T) {
      long ko = (long)(kt + 1) << 5;
      char* an = (char*)As + (bsel ^ 1) * 8192;
      char* bn = (char*)Bs + (bsel ^ 1) * 8192;
      GL_LDS16(Ab + ga0 + ko, an + wb);
      GL_LDS16(Ab + ga0 + gstep + ko, an + 4096 + wb);
      GL_LDS16(Bb + ga0 + ko, bn + wb);
      GL_LDS16(Bb + ga0 + gstep + ko, bn + 4096 + wb);
    }
    char* ac = (char*)As + bsel * 8192;
    char* bc = (char*)Bs + bsel * 8192;
    bf16x8 af[4], bq[4];
#pragma unroll
    for (int i = 0; i < 4; ++i) {
      af[i] = __builtin_bit_cast(bf16x8, *(const u32x4*)(ac + aoff[i]));
      bq[i] = __builtin_bit_cast(bf16x8, *(const u32x4*)(bc + boff[i]));
    }
#pragma unroll
    for (int i = 0; i < 4; ++i)
#pragma unroll
      for (int j = 0; j < 4; ++j)
        acc[i][j] = __builtin_amdgcn_mfma_f32_16x16x32_bf16(af[i], bq[j], acc[i][j], 0, 0, 0);
    __syncthreads();
    bsel ^= 1;
  }

  long row0 = (long)blockIdx.x * 128 + wr * 64;
  int col0 = blockIdx.y * 128 + wc * 64;
  float* cf = Cf ? Cf + bz * sC : (float*)0;
  u16* cb = Cb ? Cb + bz * sC : (u16*)0;
  const float* ldv = logdv ? logdv + bz * 256 : (const float*)0;
#pragma unroll
  for (int i = 0; i < 4; ++i) {
    long rb0 = row0 + i * 16 + lg * 4;
#pragma unroll
    for (int j = 0; j < 4; ++j) {
      int c = col0 + j * 16 + li;
      float bv = bias ? bias[c] : 0.f;
      float lj = ldv ? ldv[c] : 0.f;
#pragma unroll
      for (int r = 0; r < 4; ++r) {
        float v = acc[i][j][r] * alpha + bv;
        if (ldv) v += fabsf(ldv[rb0 + r] - lj);
        if (act) v = 0.5f * v * (1.f + erff(v * 0.70710678118f));
        long row = rb0 + r;
        long idx = tstore ? ((row >> 8) * 196608 + (long)c * 256 + (row & 255))
                          : (row * ldc + c);
        if (cf) cf[idx] = v;
        if (cb) cb[idx] = f2bf(v);
      }
    }
  }
}

// ------- fused MHA: one block per (b, h); 8 waves; K/V staged ONCE -------
// 512 threads. LDS (dynamic 128KB): Ks 32KB | Vt 32KB | Ps 64KB (8KB/wave).
__global__ __launch_bounds__(512) void mha_k(const u16* __restrict__ qkv, u16* __restrict__ obf) {
  extern __shared__ __align__(16) char smh[];
  u16* Ks = (u16*)smh;                  // [256][64] swizzled
  u16* Vt = (u16*)(smh + 32768);        // [64][256] swizzled
  char* Pw0 = smh + 65536;              // per-wave [16][256] swizzled
  int b = blockIdx.y;
  int h = blockIdx.x;
  int tid = threadIdx.x, w = tid >> 6, l = tid & 63, lg = l >> 4, li = l & 15;
  const u16* kb_ = qkv + (long)b * 256 * 2304 + 768 + h * 64;
  const u16* vb_ = qkv + (long)b * 256 * 2304 + 1536 + h * 64;
#pragma unroll
  for (int it = 0; it < 4; ++it) {
    int c = it * 512 + tid; int n = c >> 3, sl = c & 7;
    u32x4 d = *(const u32x4*)(kb_ + (long)n * 2304 + sl * 8);
    *(u32x4*)((char*)Ks + n * 128 + ((sl ^ (n & 7)) << 4)) = d;
  }
#pragma unroll
  for (int it = 0; it < 4; ++it) {
    int c = it * 512 + tid; int n = c >> 3, sl = c & 7;
    u32x4 dv = *(const u32x4*)(vb_ + (long)n * 2304 + sl * 8);
    const u16* pe = (const u16*)&dv;
#pragma unroll
    for (int j = 0; j < 8; ++j) {
      int dd = sl * 8 + j;
      *(u16*)((char*)Vt + dd * 512 + (((n >> 3) ^ (dd & 7)) << 4) + (n & 7) * 2) = pe[j];
    }
  }
  __syncthreads();

  char* Ps = Pw0 + w * 8192;
  for (int half = 0; half < 2; ++half) {
    long qrow = (long)b * 256 + half * 128 + w * 16 + li;
    const u16* qp = qkv + qrow * 2304 + h * 64;
    bf16x8 qf0 = __builtin_bit_cast(bf16x8, *(const u32x4*)(qp + lg * 8));
    bf16x8 qf1 = __builtin_bit_cast(bf16x8, *(const u32x4*)(qp + 32 + lg * 8));

    f32x4 sacc[16] = {};
#pragma unroll
    for (int jt = 0; jt < 16; ++jt) {
      int j = jt * 16 + li;
      u32x4 k0 = *(const u32x4*)((char*)Ks + j * 128 + ((lg ^ (j & 7)) << 4));
      u32x4 k1 = *(const u32x4*)((char*)Ks + j * 128 + (((4 + lg) ^ (j & 7)) << 4));
      sacc[jt] = __builtin_amdgcn_mfma_f32_16x16x32_bf16(qf0, __builtin_bit_cast(bf16x8, k0), sacc[jt], 0, 0, 0);
      sacc[jt] = __builtin_amdgcn_mfma_f32_16x16x32_bf16(qf1, __builtin_bit_cast(bf16x8, k1), sacc[jt], 0, 0, 0);
    }
#pragma unroll
    for (int jt = 0; jt < 16; ++jt) sacc[jt] = sacc[jt] * 0.125f;

    float rinv[4];
#pragma unroll
    for (int r = 0; r < 4; ++r) {
      float m = -1e30f;
#pragma unroll
      for (int jt = 0; jt < 16; ++jt) m = fmaxf(m, sacc[jt][r]);
#pragma unroll
      for (int mk = 1; mk < 16; mk <<= 1) m = fmaxf(m, __shfl_xor(m, mk));
      float s = 0.f;
#pragma unroll
      for (int jt = 0; jt < 16; ++jt) { float e = __expf(sacc[jt][r] - m); sacc[jt][r] = e; s += e; }
#pragma unroll
      for (int mk = 1; mk < 16; mk <<= 1) s += __shfl_xor(s, mk);
      rinv[r] = 1.f / s;
    }
#pragma unroll
    for (int jt = 0; jt < 16; ++jt) {
      int j = jt * 16 + li;
#pragma unroll
      for (int r = 0; r < 4; ++r) {
        int i = lg * 4 + r;
        *(u16*)(Ps + i * 512 + (((j >> 3) ^ (i & 7)) << 4) + (j & 7) * 2) = f2bf(sacc[jt][r]);
      }
    }
    __syncthreads();
    f32x4 oacc[4] = {};
#pragma unroll
    for (int kb2 = 0; kb2 < 8; ++kb2) {
      int sl = kb2 * 4 + lg;
      u32x4 pa = *(const u32x4*)(Ps + li * 512 + ((sl ^ (li & 7)) << 4));
#pragma unroll
      for (int dt = 0; dt < 4; ++dt) {
        int dd = dt * 16 + li;
        u32x4 vv = *(const u32x4*)((char*)Vt + dd * 512 + ((sl ^ (dd & 7)) << 4));
        oacc[dt] = __builtin_amdgcn_mfma_f32_16x16x32_bf16(__builtin_bit_cast(bf16x8, pa),
                                                           __builtin_bit_cast(bf16x8, vv), oacc[dt], 0, 0, 0);
      }
    }
    long orow = (long)b * 256 + half * 128 + w * 16;
#pragma unroll
    for (int dt = 0; dt < 4; ++dt)
#pragma unroll
      for (int r = 0; r < 4; ++r) {
        float vvv = oacc[dt][r] * rinv[r];
        obf[(orow + lg * 4 + r) * 768 + h * 64 + dt * 16 + li] = f2bf(vvv);
      }
  }
}

// -------- LayerNorm(x + res), all bf16 in / bf16 out (wave per row) --------
__global__ __launch_bounds__(256) void ln_k(const u16* __restrict__ X, const u16* __restrict__ Rr,
                                            const float* __restrict__ g, const float* __restrict__ bb,
                                            u16* __restrict__ O) {
  long row = (long)blockIdx.x * 4 + (threadIdx.x >> 6);
  int l = threadIdx.x & 63;
  const u16* x = X + row * 768;
  const u16* rr = Rr + row * 768;
  f32x4 v[3];
  float s = 0.f;
#pragma unroll
  for (int i = 0; i < 3; ++i) {
    u16x4 xv = *(const u16x4*)(x + i * 256 + l * 4);
    u16x4 rv = *(const u16x4*)(rr + i * 256 + l * 4);
    f32x4 t;
#pragma unroll
    for (int j = 0; j < 4; ++j) t[j] = bf2f(xv[j]) + bf2f(rv[j]);
    v[i] = t;
    s += t[0] + t[1] + t[2] + t[3];
  }
  float mean = wredSum(s) * (1.f / 768.f);
  float q = 0.f;
#pragma unroll
  for (int i = 0; i < 3; ++i) {
#pragma unroll
    for (int j = 0; j < 4; ++j) { v[i][j] -= mean; q += v[i][j] * v[i][j]; }
  }
  float inv = rsqrtf(wredSum(q) * (1.f / 768.f) + 1e-5f);
#pragma unroll
  for (int i = 0; i < 3; ++i) {
    f32x4 gv = *(const f32x4*)(g + i * 256 + l * 4);
    f32x4 bv = *(const f32x4*)(bb + i * 256 + l * 4);
    u16x4 ob;
#pragma unroll
    for (int j = 0; j < 4; ++j) ob[j] = f2bf(v[i][j] * inv * gv[j] + bv[j]);
    *(u16x4*)(O + row * 768 + i * 256 + l * 4) = ob;
  }
}

// ---------------- semantic softmax ----------------
__global__ __launch_bounds__(256) void smax_k(const float* __restrict__ S, u16* __restrict__ P) {
  long row = (long)blockIdx.x * 4 + (threadIdx.x >> 6);
  int l = threadIdx.x & 63;
  f32x4 v = *(const f32x4*)(S + row * 256 + l * 4);
  float m = fmaxf(fmaxf(v[0], v[1]), fmaxf(v[2], v[3]));
#pragma unroll
  for (int mk = 1; mk < 64; mk <<= 1) m = fmaxf(m, __shfl_xor(m, mk));
  float e0 = __expf(v[0] - m), e1 = __expf(v[1] - m), e2 = __expf(v[2] - m), e3 = __expf(v[3] - m);
  float s = wredSum(e0 + e1 + e2 + e3);
  float rn = 1.f / s;
  u16x4 o; o[0] = f2bf(e0 * rn); o[1] = f2bf(e1 * rn); o[2] = f2bf(e2 * rn); o[3] = f2bf(e3 * rn);
  *(u16x4*)(P + row * 256 + l * 4) = o;
}

__global__ __launch_bounds__(256) void conv_k(const float* __restrict__ in, u16* __restrict__ out, long n4) {
  long i = (long)blockIdx.x * 256 + threadIdx.x;
  if (i >= n4) return;
  f32x4 v = *(const f32x4*)(in + i * 4);
  u16x4 o; o[0] = f2bf(v[0]); o[1] = f2bf(v[1]); o[2] = f2bf(v[2]); o[3] = f2bf(v[3]);
  *(u16x4*)(out + i * 4) = o;
}

// ---------------- concat ocr/obj -> x bf16 ----------------
__global__ __launch_bounds__(256) void concat_k(const float* __restrict__ ocr, const float* __restrict__ obj,
                                                u16* __restrict__ xb) {
  long i = (long)blockIdx.x * 256 + threadIdx.x;
  if (i >= 16384L * 192) return;
  long row = i / 192; int c4 = (int)(i % 192);
  int b = (int)(row >> 8), n = (int)(row & 255);
  const float* src = (n < 64) ? (ocr + ((long)(b * 64 + n)) * 768) : (obj + ((long)(b * 192 + n - 64)) * 768);
  f32x4 v = *(const f32x4*)(src + c4 * 4);
  u16x4 o; o[0] = f2bf(v[0]); o[1] = f2bf(v[1]); o[2] = f2bf(v[2]); o[3] = f2bf(v[3]);
  *(u16x4*)(xb + row * 768 + c4 * 4) = o;
}

__global__ __launch_bounds__(256) void logdv_k(const float* __restrict__ ocr_dv, const float* __restrict__ obj_dv,
                                               float* __restrict__ out) {
  int i = blockIdx.x * 256 + threadIdx.x;
  if (i >= 16384) return;
  int b = i >> 8, n = i & 255;
  float dv = (n < 64) ? ocr_dv[b * 64 + n] : obj_dv[b * 192 + n - 64];
  out[i] = logf(dv);
}

// ---------------- output slice h[:, :64, :] bf16 -> f32 ----------------
__global__ __launch_bounds__(256) void slice_k(const u16* __restrict__ H, float* __restrict__ O) {
  long i = (long)blockIdx.x * 256 + threadIdx.x;
  if (i >= 786432) return;
  long idx = i * 4;
  long row = idx / 768; int c = (int)(idx % 768);
  long b = row >> 6, n = row & 63;
  u16x4 v = *(const u16x4*)(H + ((b * 256 + n) * 768 + c));
  f32x4 o; o[0] = bf2f(v[0]); o[1] = bf2f(v[1]); o[2] = bf2f(v[2]); o[3] = bf2f(v[3]);
  *(f32x4*)(O + idx) = o;
}

extern "C" void kernel_launch(void* const* d_in, const int* in_sizes, int n_in,
                              void* d_out, int out_size, void* d_ws, size_t ws_size,
                              hipStream_t stream) {
  const float* ocr = (const float*)d_in[0];
  const float* obj = (const float*)d_in[1];
  const float* ocr_dv = (const float*)d_in[2];
  const float* obj_dv = (const float*)d_in[3];
  const float* sa_wq = (const float*)d_in[4];
  const float* sa_bq = (const float*)d_in[5];
  const float* sa_wk = (const float*)d_in[6];
  const float* sa_bk = (const float*)d_in[7];
  const float* sa_wv = (const float*)d_in[8];
  const float* sa_bv = (const float*)d_in[9];
  const float* ln0_g = (const float*)d_in[10];
  const float* ln0_b = (const float*)d_in[11];
  const float* qkv_w = (const float*)d_in[12];
  const float* qkv_b = (const float*)d_in[13];
  const float* out_w = (const float*)d_in[14];
  const float* out_b = (const float*)d_in[15];
  const float* ln1_g = (const float*)d_in[16];
  const float* ln1_b = (const float*)d_in[17];
  const float* ff1_w = (const float*)d_in[18];
  const float* ff1_b = (const float*)d_in[19];
  const float* ff2_w = (const float*)d_in[20];
  const float* ff2_b = (const float*)d_in[21];
  const float* ln2_g = (const float*)d_in[22];
  const float* ln2_b = (const float*)d_in[23];

  (void)hipFuncSetAttribute((const void*)mha_k,
                            hipFuncAttributeMaxDynamicSharedMemorySize, 131072);
  const unsigned DSMHA = 131072;

  char* ws = (char*)d_ws;
  u16* HB = (u16*)ws;                            // h bf16 [16384][768] 25.2MB
  float* LDV = (float*)(ws + 25165824);          // log(dv)             64KB

  const int bigws = ws_size >= (size_t)187236352;

  auto cv = [&](const float* src, long elems, u16* dst) {
    long n4 = elems >> 2;
    conv_k<<<dim3((unsigned)((n4 + 255) / 256)), dim3(256), 0, stream>>>(src, dst, n4);
  };

  concat_k<<<12288, 256, 0, stream>>>(ocr, obj, HB);
  logdv_k<<<64, 256, 0, stream>>>(ocr_dv, obj_dv, LDV);

  const float SSC = 0.03608439182435161f;  // 1/sqrt(768)

  if (bigws) {
    // layout: HB 25.2MB | LDV 64KB | WALL 47.6MB (all weights bf16) | SCR 101.7MB
    u16* WALL = (u16*)(ws + 25231360);
    u16* WSA = WALL;                                // 3 x 589824 semantic
    cv(sa_wq, 589824, WSA);
    cv(sa_wk, 589824, WSA + 589824);
    cv(sa_wv, 589824, WSA + 1179648);
    for (int l = 0; l < 4; ++l) {
      u16* WL = WALL + 1769472 + (long)l * 5505024;
      cv(qkv_w + (long)l * 1769472, 1769472, WL);
      cv(out_w + (long)l * 589824, 589824, WL + 1769472);
      cv(ff1_w + (long)l * 1572864, 1572864, WL + 2359296);
      cv(ff2_w + (long)l * 1572864, 1572864, WL + 3932160);
    }
    char* SCR = ws + 25231360 + 47579136;           // total 174.5MB
    // ---------- semantic attention, full-M single pass ----------
    u16* Qf = (u16*)SCR;                         // [16384][768]  25.2MB
    u16* Kf = (u16*)(SCR + 25165824);            // [16384][768]  25.2MB
    u16* VTf = (u16*)(SCR + 50331648);           // [64][768][256] 25.2MB
    float* Sff = (float*)(SCR + 75497472);       // [64][256][256] f32 16.8MB
    u16* Pf = (u16*)SCR;                         // (Q dead)
    u16* ATTf = (u16*)(SCR + 25165824);          // (K dead)
    gemmq<<<768, 256, 0, stream>>>(HB, WSA, sa_bq, Qf, 768, 768, 128, 6, 0, 0);
    gemmq<<<768, 256, 0, stream>>>(HB, WSA + 589824, sa_bk, Kf, 768, 768, 128, 6, 0, 0);
    gemmq<<<768, 256, 0, stream>>>(HB, WSA + 1179648, sa_bv, VTf, 768, 768, 128, 6, 0, 1);
    gemm_bt<<<dim3(2, 2, 64), 256, 0, stream>>>(Qf, Kf, nullptr, LDV, Sff, nullptr, 768, 256,
                                                196608, 196608, 65536, SSC, 0, 0);
    smax_k<<<4096, 256, 0, stream>>>(Sff, Pf);
    gemm_bt<<<dim3(2, 6, 64), 256, 0, stream>>>(Pf, VTf, nullptr, nullptr,
                                                nullptr, ATTf, 256, 768, 65536, 196608, 196608, 1.f, 0, 0);
    ln_k<<<4096, 256, 0, stream>>>(HB, ATTf, ln0_g, ln0_b, HB);
    // ---------- 4 encoder layers, full-M ----------
    u16* QKVf = (u16*)SCR;                       // [16384][2304] 75.5MB
    u16* Of = (u16*)(SCR + 75497472);            // [16384][768]  25.2MB
    u16* PRf = (u16*)SCR;                        // (QKV dead)
    u16* FFf = (u16*)(SCR + 25165824);           // (O dead)
    for (int l = 0; l < 4; ++l) {
      u16* WL = WALL + 1769472 + (long)l * 5505024;
      gemmq<<<768, 256, 0, stream>>>(HB, WL, qkv_b + l * 2304, QKVf, 768, 2304, 128, 18, 0, 0);
      mha_k<<<dim3(12, 64), 512, DSMHA, stream>>>(QKVf, Of);
      gemmq<<<768, 256, 0, stream>>>(Of, WL + 1769472, out_b + l * 768, PRf, 768, 768, 128, 6, 0, 0);
      ln_k<<<4096, 256, 0, stream>>>(HB, PRf, ln1_g + l * 768, ln1_b + l * 768, HB);
      gemmq<<<768, 256, 0, stream>>>(HB, WL + 2359296, ff1_b + l * 2048, FFf, 768, 2048, 128, 16, 1, 0);
      gemmq<<<768, 256, 0, stream>>>(FFf, WL + 3932160, ff2_b + l * 768, PRf, 2048, 768, 128, 6, 0, 0);
      ln_k<<<4096, 256, 0, stream>>>(HB, PRf, ln2_g + l * 768, ln2_b + l * 768, HB);
    }
  } else {
    // ---------- fallback: rotating 11MB weight buf + chunked (proven) ----------
    u16* WCV = (u16*)(ws + 25231360);
    char* SCR = ws + 36241408;
    cv(sa_wq, 589824, WCV);
    cv(sa_wk, 589824, WCV + 589824);
    cv(sa_wv, 589824, WCV + 1179648);
    for (int c = 0; c < 2; ++c) {
      long base = (long)c * 8192;
      u16* Qc = (u16*)SCR;
      u16* Kc = (u16*)(SCR + 12582912);
      u16* VTc = (u16*)(SCR + 25165824);
      float* Sfc = (float*)(SCR + 37748736);
      u16* Pc = (u16*)(SCR + 46137344);
      u16* ATTc = (u16*)(SCR + 50331648);
      gemmq<<<768, 256, 0, stream>>>(HB + base * 768, WCV, sa_bq, Qc, 768, 768, 64, 6, 0, 0);
      gemmq<<<768, 256, 0, stream>>>(HB + base * 768, WCV + 589824, sa_bk, Kc, 768, 768, 64, 6, 0, 0);
      gemmq<<<768, 256, 0, stream>>>(HB + base * 768, WCV + 1179648, sa_bv, VTc, 768, 768, 64, 6, 0, 1);
      gemm_bt<<<dim3(2, 2, 32), 256, 0, stream>>>(Qc, Kc, nullptr, LDV + c * 8192,
                                                  Sfc, nullptr, 768, 256, 196608, 196608, 65536, SSC, 0, 0);
      smax_k<<<2048, 256, 0, stream>>>(Sfc, Pc);
      gemm_bt<<<dim3(2, 6, 32), 256, 0, stream>>>(Pc, VTc, nullptr, nullptr,
                                                  nullptr, ATTc, 256, 768, 65536, 196608, 196608, 1.f, 0, 0);
      ln_k<<<2048, 256, 0, stream>>>(HB + base * 768, ATTc, ln0_g, ln0_b, HB + base * 768);
    }
    for (int l = 0; l < 4; ++l) {
      cv(qkv_w + (long)l * 1769472, 1769472, WCV);
      cv(out_w + (long)l * 589824, 589824, WCV + 1769472);
      cv(ff1_w + (long)l * 1572864, 1572864, WCV + 2359296);
      cv(ff2_w + (long)l * 1572864, 1572864, WCV + 3932160);
      for (int c = 0; c < 2; ++c) {
        long base = (long)c * 8192;
        u16* QKVc = (u16*)SCR;
        u16* Oc = (u16*)(SCR + 37748736);
        u16* PRc = (u16*)(SCR + 50331648);
        u16* FFc = (u16*)SCR;
        gemmq<<<768, 256, 0, stream>>>(HB + base * 768, WCV, qkv_b + l * 2304, QKVc, 768, 2304, 64, 18, 0, 0);
        mha_k<<<dim3(12, 32), 512, DSMHA, stream>>>(QKVc, Oc);
        gemmq<<<768, 256, 0, stream>>>(Oc, WCV + 1769472, out_b + l * 768, PRc, 768, 768, 64, 6, 0, 0);
        ln_k<<<2048, 256, 0, stream>>>(HB + base * 768, PRc, ln1_g + l * 768, ln1_b + l * 768, HB + base * 768);
        gemmq<<<768, 256, 0, stream>>>(HB + base * 768, WCV + 2359296, ff1_b + l * 2048, FFc, 768, 2048, 64, 16, 1, 0);
        gemmq<<<768, 256, 0, stream>>>(FFc, WCV + 3932160, ff2_b + l * 768, PRc, 2048, 768, 64, 6, 0, 0);
        ln_k<<<2048, 256, 0, stream>>>(HB + base * 768, PRc, ln2_g + l * 768, ln2_b + l * 768, HB + base * 768);
      }
    }
  }
  slice_k<<<3072, 256, 0, stream>>>(HB, (float*)d_out);
}

// Round 20
// 1622.060 us; speedup vs baseline: 2.4173x; 1.0025x over previous
//
#include <hip/hip_runtime.h>

typedef unsigned short u16;
typedef __bf16 bf16_t;
typedef bf16_t bf16x8 __attribute__((ext_vector_type(8)));
typedef float f32x4 __attribute__((ext_vector_type(4)));
typedef unsigned int u32x4 __attribute__((ext_vector_type(4)));
typedef u16 u16x4 __attribute__((ext_vector_type(4)));

#define GL_LDS16(gp, lp)                                              \
  __builtin_amdgcn_global_load_lds(                                   \
      (const __attribute__((address_space(1))) void*)(gp),            \
      (__attribute__((address_space(3))) void*)(lp), 16, 0, 0)

__device__ __forceinline__ u16 f2bf(float f) {
  unsigned u = __builtin_bit_cast(unsigned, f);
  u += 0x7fff + ((u >> 16) & 1);   // RNE
  return (u16)(u >> 16);
}
__device__ __forceinline__ float bf2f(u16 h) {
  unsigned u = ((unsigned)h) << 16;
  return __builtin_bit_cast(float, u);
}
__device__ __forceinline__ float wredSum(float v) {
#pragma unroll
  for (int m = 32; m; m >>= 1) v += __shfl_xor(v, m);
  return v;
}
// tanh-form GELU via fast exp (~8 VALU ops). |err| <= ~1e-3.
__device__ __forceinline__ float gelu_fast(float v) {
  float t = 0.7978845608f * v * (1.f + 0.044715f * v * v);
  float e = __expf(2.f * t);
  float th = 1.f - 2.f / (e + 1.f);
  return 0.5f * v * (1.f + th);
}

// ===== persistent 128x128-tile rolling bf16 NT GEMM, 3 blocks/CU (r17) =====
// C[M,N]=A[M,K]*B[N,K]^T. BK=32, 3 LDS buf x 16KB = 48KB static
// -> 3 blocks/CU (144KB), 12 waves/CU, 68 VGPR (no spill; r18's 5 blocks/CU
// capped VGPR at ~96 -> acc spilled to scratch, WRITE 80->718MB, 2.4x slower).
// Ledger: prologue u0,u1 (8 in flight); iter s: vmcnt(4) [retire u_s]
// -> barrier -> stage u_{s+2} -> ds_read -> MFMA. Epilogue ends with VM0
// (stores count toward vmcnt; ledger stays exact across tiles).
// r20: s_setprio removed (T5 is 8-phase-conditional; m190 shows ~0 to
// negative on lockstep GEMM structures like this one).
// Supertile: XCD x owns mt-slab [x*G,(x+1)*G), G=gx/8.
__global__ __launch_bounds__(256, 3) void gemmq(
    const u16* __restrict__ A, const u16* __restrict__ B,
    const float* __restrict__ bias, u16* __restrict__ C,
    int K, int N, int gx, int gy, int act, int tstore) {
  __shared__ __align__(16) char sm[3 * 16384];  // 3 x (A 8KB | B 8KB)
  const int tid = threadIdx.x;
  const int l = tid & 63, w = tid >> 6, lg = l >> 4, li = l & 15;
  const int wr = w >> 1, wc = w & 1;
  const int TOT = gx * gy;
  int tix = blockIdx.x;
  if (tix >= TOT) return;
  const int G = gx >> 3;   // gx % 8 == 0

  const long rowK64 = (long)64 * K;
  const long saoff = (long)(tid >> 2) * K + (((tid & 3) ^ ((tid >> 3) & 3)) << 3);
  const int t16 = tid * 16;

#define STAGE(bi_, Ap_, Bp_, kt_)                                      \
  do {                                                                 \
    char* lb_ = sm + (bi_) * 16384;                                    \
    const u16* ga_ = (Ap_) + saoff + ((long)(kt_) << 5);               \
    GL_LDS16(ga_, lb_ + t16);                                          \
    GL_LDS16(ga_ + rowK64, lb_ + 4096 + t16);                          \
    const u16* gb_ = (Bp_) + saoff + ((long)(kt_) << 5);               \
    GL_LDS16(gb_, lb_ + 8192 + t16);                                   \
    GL_LDS16(gb_ + rowK64, lb_ + 12288 + t16);                         \
  } while (0)

#define VM4 asm volatile("s_waitcnt vmcnt(4)" ::: "memory")
#define VM0 asm volatile("s_waitcnt vmcnt(0)" ::: "memory")

  // ds_read offsets (XOR swizzle slot' = lg ^ ((row>>1)&3); 0 conflicts)
  int aof[4], bof[4];
#pragma unroll
  for (int f = 0; f < 4; ++f) {
    int ra = wr * 64 + f * 16 + li;
    aof[f] = ra * 64 + ((lg ^ ((ra >> 1) & 3)) << 4);
    int rb = wc * 64 + f * 16 + li;
    bof[f] = 8192 + rb * 64 + ((lg ^ ((rb >> 1) & 3)) << 4);
  }

  int mt, nt;
  const u16 *cA, *cB;
  { int xc = tix & 7, lo = tix >> 3;
    mt = xc * G + lo % G; nt = lo / G;
    cA = A + (long)mt * 128 * K; cB = B + (long)nt * 128 * K; }
  int nxt = tix + 768;
  int hasn = nxt < TOT;
  int nmt = 0, nnt = 0;
  const u16 *nA = cA, *nB = cB;
  if (hasn) { int xc = nxt & 7, lo = nxt >> 3;
    nmt = xc * G + lo % G; nnt = lo / G;
    nA = A + (long)nmt * 128 * K; nB = B + (long)nnt * 128 * K; }

  const int NT = K >> 5;  // K % 32 == 0, NT >= 3
  f32x4 acc[4][4] = {};
  STAGE(0, cA, cB, 0); STAGE(1, cA, cB, 1);  // 8 loads in flight
  int bi = 0;

  for (;;) {
    for (int s = 0; s < NT; ++s) {
      int bi2 = bi + 2; if (bi2 >= 3) bi2 -= 3;
      const char* ab = sm + bi * 16384;
      if (s == NT - 1 && !hasn) VM0; else VM4;
      __builtin_amdgcn_s_barrier();
      asm volatile("" ::: "memory");        // no ds_read hoists above barrier
      int s2 = s + 2;
      if (s2 < NT) STAGE(bi2, cA, cB, s2);
      else if (hasn) STAGE(bi2, nA, nB, s2 - NT);
      bf16x8 af[4], bq[4];
#pragma unroll
      for (int f = 0; f < 4; ++f) {
        af[f] = __builtin_bit_cast(bf16x8, *(const u32x4*)(ab + aof[f]));
        bq[f] = __builtin_bit_cast(bf16x8, *(const u32x4*)(ab + bof[f]));
      }
#pragma unroll
      for (int fi = 0; fi < 4; ++fi)
#pragma unroll
        for (int fj = 0; fj < 4; ++fj)
          acc[fi][fj] = __builtin_amdgcn_mfma_f32_16x16x32_bf16(af[fi], bq[fj], acc[fi][fj], 0, 0, 0);
      bi = bi + 1; if (bi == 3) bi = 0;
    }
    // ---- epilogue for current tile ----
    {
      long row0 = (long)mt * 128 + wr * 64;
      int col0 = nt * 128 + wc * 64;
#pragma unroll
      for (int fi = 0; fi < 4; ++fi) {
#pragma unroll
        for (int fj = 0; fj < 4; ++fj) {
          int c = col0 + fj * 16 + li;
          float bv = bias ? bias[c] : 0.f;
#pragma unroll
          for (int r = 0; r < 4; ++r) {
            float v = acc[fi][fj][r] + bv;
            if (act) v = gelu_fast(v);
            long row = row0 + fi * 16 + lg * 4 + r;
            long idx = tstore ? ((row >> 8) * 196608 + (long)c * 256 + (row & 255))
                              : (row * (long)N + c);
            C[idx] = f2bf(v);
          }
          acc[fi][fj] = (f32x4){0.f, 0.f, 0.f, 0.f};
        }
      }
    }
    if (!hasn) break;
    VM0;                    // drain epilogue stores: ledger stays exact
    mt = nmt; nt = nnt; cA = nA; cB = nB;
    tix = nxt; nxt += 768; hasn = nxt < TOT;
    if (hasn) { int xc = nxt & 7, lo = nxt >> 3;
      nmt = xc * G + lo % G; nnt = lo / G;
      nA = A + (long)nmt * 128 * K; nB = B + (long)nnt * 128 * K; }
  }
#undef STAGE
#undef VM4
#undef VM0
}

// ------- legacy 128x128 NT GEMM (semantic QK^T with +R epilogue, PV) -------
__global__ __launch_bounds__(256) void gemm_bt(
    const u16* __restrict__ A, const u16* __restrict__ B,
    const float* __restrict__ bias, const float* __restrict__ logdv,
    float* __restrict__ Cf, u16* __restrict__ Cb,
    int K, int ldc, long sA, long sB, long sC, float alpha, int act, int tstore) {
  __shared__ __align__(16) u16 As[2][128 * 32];
  __shared__ __align__(16) u16 Bs[2][128 * 32];
  int tid = threadIdx.x, w = tid >> 6, l = tid & 63, lg = l >> 4, li = l & 15;
  int wr = w >> 1, wc = w & 1;
  long bz = blockIdx.z;
  const u16* Ab = A + bz * sA + (long)blockIdx.x * 128 * K;
  const u16* Bb = B + bz * sB + (long)blockIdx.y * 128 * K;

  int sr = tid >> 2, ss = tid & 3;
  long ga0 = (long)sr * K + ((ss ^ ((sr >> 1) & 3)) << 3);
  long gstep = (long)K << 6;

  int aoff[4], boff[4];
#pragma unroll
  for (int i = 0; i < 4; ++i) {
    int ra = wr * 64 + i * 16 + li;
    aoff[i] = ra * 64 + ((lg ^ ((ra >> 1) & 3)) << 4);
    int rb = wc * 64 + i * 16 + li;
    boff[i] = rb * 64 + ((lg ^ ((rb >> 1) & 3)) << 4);
  }

  f32x4 acc[4][4] = {};
  int wb = w * 1024;

  GL_LDS16(Ab + ga0, (char*)As + wb);
  GL_LDS16(Ab + ga0 + gstep, (char*)As + 4096 + wb);
  GL_LDS16(Bb + ga0, (char*)Bs + wb);
  GL_LDS16(Bb + ga0 + gstep, (char*)Bs + 4096 + wb);
  __syncthreads();

  int T = K >> 5;
  int bsel = 0;
  for (int kt = 0; kt < T; ++kt) {
    if (kt + 1 < T) {
      long ko = (long)(kt + 1) << 5;
      char* an = (char*)As + (bsel ^ 1) * 8192;
      char* bn = (char*)Bs + (bsel ^ 1) * 8192;
      GL_LDS16(Ab + ga0 + ko, an + wb);
      GL_LDS16(Ab + ga0 + gstep + ko, an + 4096 + wb);
      GL_LDS16(Bb + ga0 + ko, bn + wb);
      GL_LDS16(Bb + ga0 + gstep + ko, bn + 4096 + wb);
    }
    char* ac = (char*)As + bsel * 8192;
    char* bc = (char*)Bs + bsel * 8192;
    bf16x8 af[4], bq[4];
#pragma unroll
    for (int i = 0; i < 4; ++i) {
      af[i] = __builtin_bit_cast(bf16x8, *(const u32x4*)(ac + aoff[i]));
      bq[i] = __builtin_bit_cast(bf16x8, *(const u32x4*)(bc + boff[i]));
    }
#pragma unroll
    for (int i = 0; i < 4; ++i)
#pragma unroll
      for (int j = 0; j < 4; ++j)
        acc[i][j] = __builtin_amdgcn_mfma_f32_16x16x32_bf16(af[i], bq[j], acc[i][j], 0, 0, 0);
    __syncthreads();
    bsel ^= 1;
  }

  long row0 = (long)blockIdx.x * 128 + wr * 64;
  int col0 = blockIdx.y * 128 + wc * 64;
  float* cf = Cf ? Cf + bz * sC : (float*)0;
  u16* cb = Cb ? Cb + bz * sC : (u16*)0;
  const float* ldv = logdv ? logdv + bz * 256 : (const float*)0;
#pragma unroll
  for (int i = 0; i < 4; ++i) {
    long rb0 = row0 + i * 16 + lg * 4;
#pragma unroll
    for (int j = 0; j < 4; ++j) {
      int c = col0 + j * 16 + li;
      float bv = bias ? bias[c] : 0.f;
      float lj = ldv ? ldv[c] : 0.f;
#pragma unroll
      for (int r = 0; r < 4; ++r) {
        float v = acc[i][j][r] * alpha + bv;
        if (ldv) v += fabsf(ldv[rb0 + r] - lj);
        if (act) v = 0.5f * v * (1.f + erff(v * 0.70710678118f));
        long row = rb0 + r;
        long idx = tstore ? ((row >> 8) * 196608 + (long)c * 256 + (row & 255))
                          : (row * ldc + c);
        if (cf) cf[idx] = v;
        if (cb) cb[idx] = f2bf(v);
      }
    }
  }
}

// ------- fused MHA: one block per (b, h); 8 waves; K/V staged ONCE -------
// 512 threads. LDS (dynamic 128KB): Ks 32KB | Vt 32KB | Ps 64KB (8KB/wave).
__global__ __launch_bounds__(512) void mha_k(const u16* __restrict__ qkv, u16* __restrict__ obf) {
  extern __shared__ __align__(16) char smh[];
  u16* Ks = (u16*)smh;                  // [256][64] swizzled
  u16* Vt = (u16*)(smh + 32768);        // [64][256] swizzled
  char* Pw0 = smh + 65536;              // per-wave [16][256] swizzled
  int b = blockIdx.y;
  int h = blockIdx.x;
  int tid = threadIdx.x, w = tid >> 6, l = tid & 63, lg = l >> 4, li = l & 15;
  const u16* kb_ = qkv + (long)b * 256 * 2304 + 768 + h * 64;
  const u16* vb_ = qkv + (long)b * 256 * 2304 + 1536 + h * 64;
#pragma unroll
  for (int it = 0; it < 4; ++it) {
    int c = it * 512 + tid; int n = c >> 3, sl = c & 7;
    u32x4 d = *(const u32x4*)(kb_ + (long)n * 2304 + sl * 8);
    *(u32x4*)((char*)Ks + n * 128 + ((sl ^ (n & 7)) << 4)) = d;
  }
#pragma unroll
  for (int it = 0; it < 4; ++it) {
    int c = it * 512 + tid; int n = c >> 3, sl = c & 7;
    u32x4 dv = *(const u32x4*)(vb_ + (long)n * 2304 + sl * 8);
    const u16* pe = (const u16*)&dv;
#pragma unroll
    for (int j = 0; j < 8; ++j) {
      int dd = sl * 8 + j;
      *(u16*)((char*)Vt + dd * 512 + (((n >> 3) ^ (dd & 7)) << 4) + (n & 7) * 2) = pe[j];
    }
  }
  __syncthreads();

  char* Ps = Pw0 + w * 8192;
  for (int half = 0; half < 2; ++half) {
    long qrow = (long)b * 256 + half * 128 + w * 16 + li;
    const u16* qp = qkv + qrow * 2304 + h * 64;
    bf16x8 qf0 = __builtin_bit_cast(bf16x8, *(const u32x4*)(qp + lg * 8));
    bf16x8 qf1 = __builtin_bit_cast(bf16x8, *(const u32x4*)(qp + 32 + lg * 8));

    f32x4 sacc[16] = {};
#pragma unroll
    for (int jt = 0; jt < 16; ++jt) {
      int j = jt * 16 + li;
      u32x4 k0 = *(const u32x4*)((char*)Ks + j * 128 + ((lg ^ (j & 7)) << 4));
      u32x4 k1 = *(const u32x4*)((char*)Ks + j * 128 + (((4 + lg) ^ (j & 7)) << 4));
      sacc[jt] = __builtin_amdgcn_mfma_f32_16x16x32_bf16(qf0, __builtin_bit_cast(bf16x8, k0), sacc[jt], 0, 0, 0);
      sacc[jt] = __builtin_amdgcn_mfma_f32_16x16x32_bf16(qf1, __builtin_bit_cast(bf16x8, k1), sacc[jt], 0, 0, 0);
    }
#pragma unroll
    for (int jt = 0; jt < 16; ++jt) sacc[jt] = sacc[jt] * 0.125f;

    float rinv[4];
#pragma unroll
    for (int r = 0; r < 4; ++r) {
      float m = -1e30f;
#pragma unroll
      for (int jt = 0; jt < 16; ++jt) m = fmaxf(m, sacc[jt][r]);
#pragma unroll
      for (int mk = 1; mk < 16; mk <<= 1) m = fmaxf(m, __shfl_xor(m, mk));
      float s = 0.f;
#pragma unroll
      for (int jt = 0; jt < 16; ++jt) { float e = __expf(sacc[jt][r] - m); sacc[jt][r] = e; s += e; }
#pragma unroll
      for (int mk = 1; mk < 16; mk <<= 1) s += __shfl_xor(s, mk);
      rinv[r] = 1.f / s;
    }
#pragma unroll
    for (int jt = 0; jt < 16; ++jt) {
      int j = jt * 16 + li;
#pragma unroll
      for (int r = 0; r < 4; ++r) {
        int i = lg * 4 + r;
        *(u16*)(Ps + i * 512 + (((j >> 3) ^ (i & 7)) << 4) + (j & 7) * 2) = f2bf(sacc[jt][r]);
      }
    }
    __syncthreads();
    f32x4 oacc[4] = {};
#pragma unroll
    for (int kb2 = 0; kb2 < 8; ++kb2) {
      int sl = kb2 * 4 + lg;
      u32x4 pa = *(const u32x4*)(Ps + li * 512 + ((sl ^ (li & 7)) << 4));
#pragma unroll
      for (int dt = 0; dt < 4; ++dt) {
        int dd = dt * 16 + li;
        u32x4 vv = *(const u32x4*)((char*)Vt + dd * 512 + ((sl ^ (dd & 7)) << 4));
        oacc[dt] = __builtin_amdgcn_mfma_f32_16x16x32_bf16(__builtin_bit_cast(bf16x8, pa),
                                                           __builtin_bit_cast(bf16x8, vv), oacc[dt], 0, 0, 0);
      }
    }
    long orow = (long)b * 256 + half * 128 + w * 16;
#pragma unroll
    for (int dt = 0; dt < 4; ++dt)
#pragma unroll
      for (int r = 0; r < 4; ++r) {
        float vvv = oacc[dt][r] * rinv[r];
        obf[(orow + lg * 4 + r) * 768 + h * 64 + dt * 16 + li] = f2bf(vvv);
      }
  }
}

// -------- LayerNorm(x + res), all bf16 in / bf16 out (wave per row) --------
__global__ __launch_bounds__(256) void ln_k(const u16* __restrict__ X, const u16* __restrict__ Rr,
                                            const float* __restrict__ g, const float* __restrict__ bb,
                                            u16* __restrict__ O) {
  long row = (long)blockIdx.x * 4 + (threadIdx.x >> 6);
  int l = threadIdx.x & 63;
  const u16* x = X + row * 768;
  const u16* rr = Rr + row * 768;
  f32x4 v[3];
  float s = 0.f;
#pragma unroll
  for (int i = 0; i < 3; ++i) {
    u16x4 xv = *(const u16x4*)(x + i * 256 + l * 4);
    u16x4 rv = *(const u16x4*)(rr + i * 256 + l * 4);
    f32x4 t;
#pragma unroll
    for (int j = 0; j < 4; ++j) t[j] = bf2f(xv[j]) + bf2f(rv[j]);
    v[i] = t;
    s += t[0] + t[1] + t[2] + t[3];
  }
  float mean = wredSum(s) * (1.f / 768.f);
  float q = 0.f;
#pragma unroll
  for (int i = 0; i < 3; ++i) {
#pragma unroll
    for (int j = 0; j < 4; ++j) { v[i][j] -= mean; q += v[i][j] * v[i][j]; }
  }
  float inv = rsqrtf(wredSum(q) * (1.f / 768.f) + 1e-5f);
#pragma unroll
  for (int i = 0; i < 3; ++i) {
    f32x4 gv = *(const f32x4*)(g + i * 256 + l * 4);
    f32x4 bv = *(const f32x4*)(bb + i * 256 + l * 4);
    u16x4 ob;
#pragma unroll
    for (int j = 0; j < 4; ++j) ob[j] = f2bf(v[i][j] * inv * gv[j] + bv[j]);
    *(u16x4*)(O + row * 768 + i * 256 + l * 4) = ob;
  }
}

// ---------------- semantic softmax ----------------
__global__ __launch_bounds__(256) void smax_k(const float* __restrict__ S, u16* __restrict__ P) {
  long row = (long)blockIdx.x * 4 + (threadIdx.x >> 6);
  int l = threadIdx.x & 63;
  f32x4 v = *(const f32x4*)(S + row * 256 + l * 4);
  float m = fmaxf(fmaxf(v[0], v[1]), fmaxf(v[2], v[3]));
#pragma unroll
  for (int mk = 1; mk < 64; mk <<= 1) m = fmaxf(m, __shfl_xor(m, mk));
  float e0 = __expf(v[0] - m), e1 = __expf(v[1] - m), e2 = __expf(v[2] - m), e3 = __expf(v[3] - m);
  float s = wredSum(e0 + e1 + e2 + e3);
  float rn = 1.f / s;
  u16x4 o; o[0] = f2bf(e0 * rn); o[1] = f2bf(e1 * rn); o[2] = f2bf(e2 * rn); o[3] = f2bf(e3 * rn);
  *(u16x4*)(P + row * 256 + l * 4) = o;
}

__global__ __launch_bounds__(256) void conv_k(const float* __restrict__ in, u16* __restrict__ out, long n4) {
  long i = (long)blockIdx.x * 256 + threadIdx.x;
  if (i >= n4) return;
  f32x4 v = *(const f32x4*)(in + i * 4);
  u16x4 o; o[0] = f2bf(v[0]); o[1] = f2bf(v[1]); o[2] = f2bf(v[2]); o[3] = f2bf(v[3]);
  *(u16x4*)(out + i * 4) = o;
}

// ---------------- concat ocr/obj -> x bf16 ----------------
__global__ __launch_bounds__(256) void concat_k(const float* __restrict__ ocr, const float* __restrict__ obj,
                                                u16* __restrict__ xb) {
  long i = (long)blockIdx.x * 256 + threadIdx.x;
  if (i >= 16384L * 192) return;
  long row = i / 192; int c4 = (int)(i % 192);
  int b = (int)(row >> 8), n = (int)(row & 255);
  const float* src = (n < 64) ? (ocr + ((long)(b * 64 + n)) * 768) : (obj + ((long)(b * 192 + n - 64)) * 768);
  f32x4 v = *(const f32x4*)(src + c4 * 4);
  u16x4 o; o[0] = f2bf(v[0]); o[1] = f2bf(v[1]); o[2] = f2bf(v[2]); o[3] = f2bf(v[3]);
  *(u16x4*)(xb + row * 768 + c4 * 4) = o;
}

__global__ __launch_bounds__(256) void logdv_k(const float* __restrict__ ocr_dv, const float* __restrict__ obj_dv,
                                               float* __restrict__ out) {
  int i = blockIdx.x * 256 + threadIdx.x;
  if (i >= 16384) return;
  int b = i >> 8, n = i & 255;
  float dv = (n < 64) ? ocr_dv[b * 64 + n] : obj_dv[b * 192 + n - 64];
  out[i] = logf(dv);
}

// ---------------- output slice h[:, :64, :] bf16 -> f32 ----------------
__global__ __launch_bounds__(256) void slice_k(const u16* __restrict__ H, float* __restrict__ O) {
  long i = (long)blockIdx.x * 256 + threadIdx.x;
  if (i >= 786432) return;
  long idx = i * 4;
  long row = idx / 768; int c = (int)(idx % 768);
  long b = row >> 6, n = row & 63;
  u16x4 v = *(const u16x4*)(H + ((b * 256 + n) * 768 + c));
  f32x4 o; o[0] = bf2f(v[0]); o[1] = bf2f(v[1]); o[2] = bf2f(v[2]); o[3] = bf2f(v[3]);
  *(f32x4*)(O + idx) = o;
}

extern "C" void kernel_launch(void* const* d_in, const int* in_sizes, int n_in,
                              void* d_out, int out_size, void* d_ws, size_t ws_size,
                              hipStream_t stream) {
  const float* ocr = (const float*)d_in[0];
  const float* obj = (const float*)d_in[1];
  const float* ocr_dv = (const float*)d_in[2];
  const float* obj_dv = (const float*)d_in[3];
  const float* sa_wq = (const float*)d_in[4];
  const float* sa_bq = (const float*)d_in[5];
  const float* sa_wk = (const float*)d_in[6];
  const float* sa_bk = (const float*)d_in[7];
  const float* sa_wv = (const float*)d_in[8];
  const float* sa_bv = (const float*)d_in[9];
  const float* ln0_g = (const float*)d_in[10];
  const float* ln0_b = (const float*)d_in[11];
  const float* qkv_w = (const float*)d_in[12];
  const float* qkv_b = (const float*)d_in[13];
  const float* out_w = (const float*)d_in[14];
  const float* out_b = (const float*)d_in[15];
  const float* ln1_g = (const float*)d_in[16];
  const float* ln1_b = (const float*)d_in[17];
  const float* ff1_w = (const float*)d_in[18];
  const float* ff1_b = (const float*)d_in[19];
  const float* ff2_w = (const float*)d_in[20];
  const float* ff2_b = (const float*)d_in[21];
  const float* ln2_g = (const float*)d_in[22];
  const float* ln2_b = (const float*)d_in[23];

  (void)hipFuncSetAttribute((const void*)mha_k,
                            hipFuncAttributeMaxDynamicSharedMemorySize, 131072);
  const unsigned DSMHA = 131072;

  char* ws = (char*)d_ws;
  u16* HB = (u16*)ws;                            // h bf16 [16384][768] 25.2MB
  float* LDV = (float*)(ws + 25165824);          // log(dv)             64KB

  const int bigws = ws_size >= (size_t)187236352;

  auto cv = [&](const float* src, long elems, u16* dst) {
    long n4 = elems >> 2;
    conv_k<<<dim3((unsigned)((n4 + 255) / 256)), dim3(256), 0, stream>>>(src, dst, n4);
  };

  concat_k<<<12288, 256, 0, stream>>>(ocr, obj, HB);
  logdv_k<<<64, 256, 0, stream>>>(ocr_dv, obj_dv, LDV);

  const float SSC = 0.03608439182435161f;  // 1/sqrt(768)

  if (bigws) {
    // layout: HB 25.2MB | LDV 64KB | WALL 47.6MB (all weights bf16) | SCR 101.7MB
    u16* WALL = (u16*)(ws + 25231360);
    u16* WSA = WALL;                                // 3 x 589824 semantic
    cv(sa_wq, 589824, WSA);
    cv(sa_wk, 589824, WSA + 589824);
    cv(sa_wv, 589824, WSA + 1179648);
    for (int l = 0; l < 4; ++l) {
      u16* WL = WALL + 1769472 + (long)l * 5505024;
      cv(qkv_w + (long)l * 1769472, 1769472, WL);
      cv(out_w + (long)l * 589824, 589824, WL + 1769472);
      cv(ff1_w + (long)l * 1572864, 1572864, WL + 2359296);
      cv(ff2_w + (long)l * 1572864, 1572864, WL + 3932160);
    }
    char* SCR = ws + 25231360 + 47579136;           // total 174.5MB
    // ---------- semantic attention, full-M single pass ----------
    u16* Qf = (u16*)SCR;                         // [16384][768]  25.2MB
    u16* Kf = (u16*)(SCR + 25165824);            // [16384][768]  25.2MB
    u16* VTf = (u16*)(SCR + 50331648);           // [64][768][256] 25.2MB
    float* Sff = (float*)(SCR + 75497472);       // [64][256][256] f32 16.8MB
    u16* Pf = (u16*)SCR;                         // (Q dead)
    u16* ATTf = (u16*)(SCR + 25165824);          // (K dead)
    gemmq<<<768, 256, 0, stream>>>(HB, WSA, sa_bq, Qf, 768, 768, 128, 6, 0, 0);
    gemmq<<<768, 256, 0, stream>>>(HB, WSA + 589824, sa_bk, Kf, 768, 768, 128, 6, 0, 0);
    gemmq<<<768, 256, 0, stream>>>(HB, WSA + 1179648, sa_bv, VTf, 768, 768, 128, 6, 0, 1);
    gemm_bt<<<dim3(2, 2, 64), 256, 0, stream>>>(Qf, Kf, nullptr, LDV, Sff, nullptr, 768, 256,
                                                196608, 196608, 65536, SSC, 0, 0);
    smax_k<<<4096, 256, 0, stream>>>(Sff, Pf);
    gemm_bt<<<dim3(2, 6, 64), 256, 0, stream>>>(Pf, VTf, nullptr, nullptr,
                                                nullptr, ATTf, 256, 768, 65536, 196608, 196608, 1.f, 0, 0);
    ln_k<<<4096, 256, 0, stream>>>(HB, ATTf, ln0_g, ln0_b, HB);
    // ---------- 4 encoder layers, full-M ----------
    u16* QKVf = (u16*)SCR;                       // [16384][2304] 75.5MB
    u16* Of = (u16*)(SCR + 75497472);            // [16384][768]  25.2MB
    u16* PRf = (u16*)SCR;                        // (QKV dead)
    u16* FFf = (u16*)(SCR + 25165824);           // (O dead)
    for (int l = 0; l < 4; ++l) {
      u16* WL = WALL + 1769472 + (long)l * 5505024;
      gemmq<<<768, 256, 0, stream>>>(HB, WL, qkv_b + l * 2304, QKVf, 768, 2304, 128, 18, 0, 0);
      mha_k<<<dim3(12, 64), 512, DSMHA, stream>>>(QKVf, Of);
      gemmq<<<768, 256, 0, stream>>>(Of, WL + 1769472, out_b + l * 768, PRf, 768, 768, 128, 6, 0, 0);
      ln_k<<<4096, 256, 0, stream>>>(HB, PRf, ln1_g + l * 768, ln1_b + l * 768, HB);
      gemmq<<<768, 256, 0, stream>>>(HB, WL + 2359296, ff1_b + l * 2048, FFf, 768, 2048, 128, 16, 1, 0);
      gemmq<<<768, 256, 0, stream>>>(FFf, WL + 3932160, ff2_b + l * 768, PRf, 2048, 768, 128, 6, 0, 0);
      ln_k<<<4096, 256, 0, stream>>>(HB, PRf, ln2_g + l * 768, ln2_b + l * 768, HB);
    }
  } else {
    // ---------- fallback: rotating 11MB weight buf + chunked (proven) ----------
    u16* WCV = (u16*)(ws + 25231360);
    char* SCR = ws + 36241408;
    cv(sa_wq, 589824, WCV);
    cv(sa_wk, 589824, WCV + 589824);
    cv(sa_wv, 589824, WCV + 1179648);
    for (int c = 0; c < 2; ++c) {
      long base = (long)c * 8192;
      u16* Qc = (u16*)SCR;
      u16* Kc = (u16*)(SCR + 12582912);
      u16* VTc = (u16*)(SCR + 25165824);
      float* Sfc = (float*)(SCR + 37748736);
      u16* Pc = (u16*)(SCR + 46137344);
      u16* ATTc = (u16*)(SCR + 50331648);
      gemmq<<<768, 256, 0, stream>>>(HB + base * 768, WCV, sa_bq, Qc, 768, 768, 64, 6, 0, 0);
      gemmq<<<768, 256, 0, stream>>>(HB + base * 768, WCV + 589824, sa_bk, Kc, 768, 768, 64, 6, 0, 0);
      gemmq<<<768, 256, 0, stream>>>(HB + base * 768, WCV + 1179648, sa_bv, VTc, 768, 768, 64, 6, 0, 1);
      gemm_bt<<<dim3(2, 2, 32), 256, 0, stream>>>(Qc, Kc, nullptr, LDV + c * 8192,
                                                  Sfc, nullptr, 768, 256, 196608, 196608, 65536, SSC, 0, 0);
      smax_k<<<2048, 256, 0, stream>>>(Sfc, Pc);
      gemm_bt<<<dim3(2, 6, 32), 256, 0, stream>>>(Pc, VTc, nullptr, nullptr,
                                                  nullptr, ATTc, 256, 768, 65536, 196608, 196608, 1.f, 0, 0);
      ln_k<<<2048, 256, 0, stream>>>(HB + base * 768, ATTc, ln0_g, ln0_b, HB + base * 768);
    }
    for (int l = 0; l < 4; ++l) {
      cv(qkv_w + (long)l * 1769472, 1769472, WCV);
      cv(out_w + (long)l * 589824, 589824, WCV + 1769472);
      cv(ff1_w + (long)l * 1572864, 1572864, WCV + 2359296);
      cv(ff2_w + (long)l * 1572864, 1572864, WCV + 3932160);
      for (int c = 0; c < 2; ++c) {
        long base = (long)c * 8192;
        u16* QKVc = (u16*)SCR;
        u16* Oc = (u16*)(SCR + 37748736);
        u16* PRc = (u16*)(SCR + 50331648);
        u16* FFc = (u16*)SCR;
        gemmq<<<768, 256, 0, stream>>>(HB + base * 768, WCV, qkv_b + l * 2304, QKVc, 768, 2304, 64, 18, 0, 0);
        mha_k<<<dim3(12, 32), 512, DSMHA, stream>>>(QKVc, Oc);
        gemmq<<<768, 256, 0, stream>>>(Oc, WCV + 1769472, out_b + l * 768, PRc, 768, 768, 64, 6, 0, 0);
        ln_k<<<2048, 256, 0, stream>>>(HB + base * 768, PRc, ln1_g + l * 768, ln1_b + l * 768, HB + base * 768);
        gemmq<<<768, 256, 0, stream>>>(HB + base * 768, WCV + 2359296, ff1_b + l * 2048, FFc, 768, 2048, 64, 16, 1, 0);
        gemmq<<<768, 256, 0, stream>>>(FFc, WCV + 3932160, ff2_b + l * 768, PRc, 2048, 768, 64, 6, 0, 0);
        ln_k<<<2048, 256, 0, stream>>>(HB + base * 768, PRc, ln2_g + l * 768, ln2_b + l * 768, HB + base * 768);
      }
    }
  }
  slice_k<<<3072, 256, 0, stream>>>(HB, (float*)d_out);
}